// Round 8
// baseline (500.544 us; speedup 1.0000x reference)
//
#include <hip/hip_runtime.h>
#include <hip/hip_bf16.h>
#include <hip/hip_fp16.h>

// RGCN: 3 layers of basis-decomposed relational graph conv + predictor.
// CSR build via 2-level counting sort (NO global atomics).
// Activations stored SLICE-MAJOR: xs[4][N][16ch] fp16 -> each 16-channel
//   slice is 3.2MB, L2-resident per XCD. slice = blockIdx&3 rides the
//   round-robin block->XCD dispatch so each XCD gathers from ITS slice only.
// k_aggregate_s: wave = 16ch x 4 edge-slots, node-sequential (no divergence),
//   2-deep unroll (8 edges in flight), shfl_xor reduce over edge-slots.
// k_gemm_mfma: out = relu([Z|x] @ [bases;loop_w] + bias) via
//   mfma_f32_16x16x32_f16, W^T fp16 + residual in LDS (~2^-22 weight error).
// Final: sigmoid(x @ pred_w + pred_b) from fp16.

#define NB1 196        // ceil(100000/512) coarse buckets
#define NBLK1 256      // L1 partition blocks
#define BUCKET_SHIFT 9 // 512 nodes per bucket
#define WT_LD 200      // padded k-stride (fp16) for W^T LDS: 400B = 2-way free

typedef unsigned short ushort_t;
typedef _Float16 h8 __attribute__((ext_vector_type(8)));
typedef float f32x4 __attribute__((ext_vector_type(4)));

__device__ inline ushort_t f2h(float f) {
  __half h = __float2half_rn(f);
  return *(ushort_t*)&h;
}
__device__ inline float h2f(ushort_t u) {
  __half h = *(__half*)&u;
  return __half2float(h);
}

// inclusive scan of one int per thread across a 256-thread block
__device__ inline int block_incl_scan_256(int v, int* wsums) {
  int lane = threadIdx.x & 63, wid = threadIdx.x >> 6;
  int s = v;
#pragma unroll
  for (int off = 1; off < 64; off <<= 1) {
    int u = __shfl_up(s, off, 64);
    if (lane >= off) s += u;
  }
  if (lane == 63) wsums[wid] = s;
  __syncthreads();
  if (threadIdx.x == 0) {
    int a = 0;
#pragma unroll
    for (int w = 0; w < 4; ++w) { int t = wsums[w]; wsums[w] = a; a += t; }
  }
  __syncthreads();
  return s + wsums[wid];
}

// ---- L1 pass a: per-block LDS histogram over 196 coarse buckets
__global__ void __launch_bounds__(256) k_l1hist(const int* __restrict__ dst,
                                                int* __restrict__ H, int E, int chunk) {
  __shared__ int h[NB1];
  int t = threadIdx.x;
  if (t < NB1) h[t] = 0;
  __syncthreads();
  int beg = blockIdx.x * chunk;
  int end = min(beg + chunk, E);
  for (int i = beg + t; i < end; i += 256) atomicAdd(&h[dst[i] >> BUCKET_SHIFT], 1);
  __syncthreads();
  if (t < NB1) H[blockIdx.x * NB1 + t] = h[t];
}

// ---- L1 pass b: scan each bucket's column of H -> excl offsets + totals
__global__ void __launch_bounds__(256) k_colscan(int* __restrict__ H,
                                                 int* __restrict__ total) {
  __shared__ int wsums[4];
  int b = blockIdx.x;
  int t = threadIdx.x;
  int v = H[t * NB1 + b];
  int s = block_incl_scan_256(v, wsums);
  H[t * NB1 + b] = s - v;
  if (t == 255) total[b] = s;
}

// ---- L1 pass c: scan bucket totals -> bucket_base
__global__ void __launch_bounds__(256) k_basescan(const int* __restrict__ total,
                                                  int* __restrict__ bucket_base,
                                                  int* __restrict__ row_off, int N) {
  __shared__ int wsums[4];
  int t = threadIdx.x;
  int v = (t < NB1) ? total[t] : 0;
  int s = block_incl_scan_256(v, wsums);
  if (t < NB1) bucket_base[t] = s - v;
  if (t == 255) { bucket_base[NB1] = s; row_off[N] = s; }
}

// ---- L1 pass d: scatter edges into bucket-partitioned epk1 via LDS cursors
__global__ void __launch_bounds__(256) k_scatter1(
    const int* __restrict__ src, const int* __restrict__ dst,
    const int* __restrict__ et, const int* __restrict__ H,
    const int* __restrict__ bucket_base, int* __restrict__ epk1,
    int E, int chunk) {
  __shared__ int cur[NB1];
  int t = threadIdx.x;
  if (t < NB1) cur[t] = bucket_base[t] + H[blockIdx.x * NB1 + t];
  __syncthreads();
  int beg = blockIdx.x * chunk;
  int end = min(beg + chunk, E);
  for (int i = beg + t; i < end; i += 256) {
    int d = dst[i];
    int b = d >> BUCKET_SHIFT;
    int p = atomicAdd(&cur[b], 1);
    epk1[p] = src[i] | (et[i] << 17) | ((d & 511) << 19);
  }
}

// ---- L2: per-bucket exact sort by dst_local (512 bins) -> epk + row_off
__global__ void __launch_bounds__(256) k_bucket(
    const int* __restrict__ epk1, const int* __restrict__ bucket_base,
    int* __restrict__ epk, int* __restrict__ row_off, int N) {
  __shared__ int hist[512];
  __shared__ int cur[512];
  __shared__ int wsums[4];
  int b = blockIdx.x;
  int t = threadIdx.x;
  int ebase = bucket_base[b], eend = bucket_base[b + 1];
  hist[t] = 0; hist[t + 256] = 0;
  __syncthreads();
  for (int i = ebase + t; i < eend; i += 256) atomicAdd(&hist[epk1[i] >> 19], 1);
  __syncthreads();
  int h0 = hist[2 * t], h1 = hist[2 * t + 1];
  int pair = h0 + h1;
  int incl = block_incl_scan_256(pair, wsums);
  int e0 = incl - pair;
  cur[2 * t] = ebase + e0;
  cur[2 * t + 1] = ebase + e0 + h0;
  int n0 = (b << BUCKET_SHIFT) + 2 * t;
  if (n0 < N) row_off[n0] = ebase + e0;
  if (n0 + 1 < N) row_off[n0 + 1] = ebase + e0 + h0;
  __syncthreads();
  for (int i = ebase + t; i < eend; i += 256) {
    int pk = epk1[i];
    int p = atomicAdd(&cur[pk >> 19], 1);
    epk[p] = pk;
  }
}

// ---- quantize fp32 -> fp16 (RTNE) into slice-major layout xs[4][N][16]
__global__ void __launch_bounds__(256) k_quant_s(const float* __restrict__ in,
                                                 ushort_t* __restrict__ out, int N) {
  int i = blockIdx.x * 256 + threadIdx.x;   // over N*16 float4 groups
  if (i >= N * 16) return;
  int node = i >> 4;
  int c0 = (i & 15) * 4;                    // channel 0..60
  float4 v = ((const float4*)in)[i];
  ushort4 q;
  q.x = f2h(v.x); q.y = f2h(v.y); q.z = f2h(v.z); q.w = f2h(v.w);
  *(ushort4*)(out + (size_t)(c0 >> 4) * N * 16 + (size_t)node * 16 + (c0 & 15)) = q;
}

// ---- sliced aggregate: slice = blockIdx&3 (rides round-robin XCD dispatch
// -> 3.2MB slice L2-resident). Wave = 16ch x 4 edge-slots, node-sequential;
// 8 edges in flight; shfl_xor reduce over edge-slots at node end.
__global__ void __launch_bounds__(256) k_aggregate_s(
    const ushort_t* __restrict__ xs, const int* __restrict__ row_off,
    const int* __restrict__ epk, const float* __restrict__ comp,
    ushort_t* __restrict__ Zh, int N) {
  __shared__ float s_comp[8];
  if (threadIdx.x < 8) s_comp[threadIdx.x] = comp[threadIdx.x];
  __syncthreads();
  int slice = blockIdx.x & 3;
  int wid = threadIdx.x >> 6, lane = threadIdx.x & 63;
  int e4 = lane >> 4, cl = lane & 15;
  const ushort_t* xsl = xs + (size_t)slice * N * 16;
  int node0 = (blockIdx.x >> 2) * 16 + wid * 4;
#pragma unroll 1
  for (int i = 0; i < 4; ++i) {
    int node = node0 + i;
    if (node >= N) break;
    int beg = row_off[node], end = row_off[node + 1];
    float z0 = 0.f, z1 = 0.f;
    for (int e = beg; e < end; e += 8) {
      int ea = e + e4, eb = e + 4 + e4;
      int pka = epk[min(ea, end - 1)];
      int pkb = epk[min(eb, end - 1)];
      float ma = (ea < end) ? 1.f : 0.f;
      float mb = (eb < end) ? 1.f : 0.f;
      int sa = pka & 0x1FFFF, ra = (pka >> 17) & 3;
      int sb = pkb & 0x1FFFF, rb = (pkb >> 17) & 3;
      float xa = h2f(xsl[(size_t)sa * 16 + cl]);
      float xb = h2f(xsl[(size_t)sb * 16 + cl]);
      float ca0 = ma * s_comp[ra * 2 + 0], ca1 = ma * s_comp[ra * 2 + 1];
      float cb0 = mb * s_comp[rb * 2 + 0], cb1 = mb * s_comp[rb * 2 + 1];
      z0 = fmaf(ca0, xa, z0); z1 = fmaf(ca1, xa, z1);
      z0 = fmaf(cb0, xb, z0); z1 = fmaf(cb1, xb, z1);
    }
    // reduce over the 4 edge-slots (lanes lane^16, lane^32, lane^48)
    z0 += __shfl_xor(z0, 16, 64); z0 += __shfl_xor(z0, 32, 64);
    z1 += __shfl_xor(z1, 16, 64); z1 += __shfl_xor(z1, 32, 64);
    if (e4 == 0)      Zh[(size_t)node * 128 + slice * 16 + cl] = f2h(z0);
    else if (e4 == 1) Zh[(size_t)node * 128 + 64 + slice * 16 + cl] = f2h(z1);
  }
}

// ---- MFMA GEMM: out = relu([Z | x](64x192 fp16) @ W(192x64) + bias)
// A-frags from global (rows read once); W^T fp16 + residual in LDS.
// Layouts (mfma_f32_16x16x32_f16): A row=l&15, k=8*(l>>4)+j;
// B k=8*(l>>4)+j, col=l&15; C/D col=l&15, row=4*(l>>4)+reg.
__global__ void __launch_bounds__(256) k_gemm_mfma(
    const ushort_t* __restrict__ Zh, const ushort_t* __restrict__ xs,
    const float* __restrict__ bases, const float* __restrict__ loopw,
    const float* __restrict__ bias, ushort_t* __restrict__ xsOut, int N) {
  __shared__ ushort_t sWh[64 * WT_LD];  // W^T fp16:      25.6 KB
  __shared__ ushort_t sWr[64 * WT_LD];  // W^T residual:  25.6 KB
  int t = threadIdx.x;
  int w = t >> 6, l = t & 63;
  int lr = l & 15, lg = l >> 4;
  int row0 = blockIdx.x * 64 + w * 16;

  // ---- issue A-frag global loads FIRST (independent of LDS staging)
  int arow = row0 + lr;
  bool rok = arow < N;
  h8 a[6];
#pragma unroll
  for (int kb = 0; kb < 6; ++kb) {
    int k0 = kb * 32 + lg * 8;
    uint4 u = make_uint4(0, 0, 0, 0);
    if (rok) {
      if (kb < 4) u = *(const uint4*)(Zh + (size_t)arow * 128 + k0);
      else {
        int kk = k0 - 128;   // channel 0..63 -> slice kk>>4, offset kk&15
        u = *(const uint4*)(xs + (size_t)(kk >> 4) * N * 16 +
                            (size_t)arow * 16 + (kk & 15));
      }
    }
    a[kb] = *(h8*)&u;
  }

  // ---- stage W^T as fp16 + residual (W = Wh + Wr exactly to ~2^-22)
#pragma unroll 4
  for (int i = 0; i < 48; ++i) {
    int idx = i * 256 + t;        // 0..12287
    int k = idx >> 6, c = idx & 63;
    float wv = (k < 128) ? bases[idx] : loopw[idx - 8192];
    ushort_t hh = f2h(wv);
    sWh[c * WT_LD + k] = hh;
    sWr[c * WT_LD + k] = f2h(wv - h2f(hh));
  }
  __syncthreads();

  // ---- MFMA: 4 col-tiles x 6 k-steps x (Wh + Wr)
  f32x4 acc[4];
#pragma unroll
  for (int c = 0; c < 4; ++c) acc[c] = (f32x4){0.f, 0.f, 0.f, 0.f};
#pragma unroll
  for (int c = 0; c < 4; ++c) {
    int col = c * 16 + lr;
    const ushort_t* bh = sWh + col * WT_LD + lg * 8;
    const ushort_t* br = sWr + col * WT_LD + lg * 8;
#pragma unroll
    for (int kb = 0; kb < 6; ++kb) {
      h8 vb = *(const h8*)(bh + kb * 32);
      acc[c] = __builtin_amdgcn_mfma_f32_16x16x32_f16(a[kb], vb, acc[c], 0, 0, 0);
      h8 vr = *(const h8*)(br + kb * 32);
      acc[c] = __builtin_amdgcn_mfma_f32_16x16x32_f16(a[kb], vr, acc[c], 0, 0, 0);
    }
  }

  // ---- epilogue: bias + relu -> fp16 activations (slice-major; slice = c)
#pragma unroll
  for (int c = 0; c < 4; ++c) {
    int col = c * 16 + lr;
    float bv = bias[col];
#pragma unroll
    for (int r = 0; r < 4; ++r) {
      int grow = row0 + lg * 4 + r;
      if (grow < N)
        xsOut[(size_t)c * N * 16 + (size_t)grow * 16 + lr] =
            f2h(fmaxf(acc[c][r] + bv, 0.f));
    }
  }
}

__global__ void __launch_bounds__(256) k_pred(
    const ushort_t* __restrict__ xs, const float* __restrict__ pw,
    const float* __restrict__ pb, float* __restrict__ out, int N) {
  int node = blockIdx.x * 4 + (threadIdx.x >> 6);
  int lane = threadIdx.x & 63;
  if (node >= N) return;
  float v = h2f(xs[(size_t)(lane >> 4) * N * 16 + (size_t)node * 16 + (lane & 15)])
            * pw[lane];
#pragma unroll
  for (int off = 32; off > 0; off >>= 1) v += __shfl_down(v, off, 64);
  if (lane == 0) {
    float logit = v + pb[0];
    out[node] = 1.f / (1.f + expf(-logit));
  }
}

extern "C" void kernel_launch(void* const* d_in, const int* in_sizes, int n_in,
                              void* d_out, int out_size, void* d_ws, size_t ws_size,
                              hipStream_t stream) {
  const float* features = (const float*)d_in[0];
  const int* src = (const int*)d_in[1];
  const int* dst = (const int*)d_in[2];
  const int* et  = (const int*)d_in[3];
  const float* bases[3] = {(const float*)d_in[4], (const float*)d_in[8],  (const float*)d_in[12]};
  const float* comp[3]  = {(const float*)d_in[5], (const float*)d_in[9],  (const float*)d_in[13]};
  const float* loopw[3] = {(const float*)d_in[6], (const float*)d_in[10], (const float*)d_in[14]};
  const float* biasp[3] = {(const float*)d_in[7], (const float*)d_in[11], (const float*)d_in[15]};
  const float* pred_w = (const float*)d_in[16];
  const float* pred_b = (const float*)d_in[17];

  const int N = in_sizes[0] / 64;   // 100000
  const int E = in_sizes[1];        // 1600000

  char* ws = (char*)d_ws;
  size_t off = 0;
  auto take = [&](size_t bytes) {
    char* p = ws + off;
    off += (bytes + 255) & ~(size_t)255;
    return p;
  };
  int*      row_off     = (int*)     take((size_t)(N + 1) * 4);
  int*      H           = (int*)     take((size_t)NBLK1 * NB1 * 4);
  int*      total       = (int*)     take((size_t)NB1 * 4);
  int*      bucket_base = (int*)     take((size_t)(NB1 + 1) * 4);
  int*      epk         = (int*)     take((size_t)(E + 8) * 4);  // +pad
  ushort_t* Zh          = (ushort_t*)take((size_t)N * 128 * 2);
  ushort_t* xsA         = (ushort_t*)take((size_t)N * 64 * 2);
  ushort_t* xsB         = (ushort_t*)take((size_t)N * 64 * 2);
  int*      epk1        = (int*)Zh;   // alias: Zh dead during CSR build
  (void)ws_size;

  // ---- CSR build: 2-level counting sort, no global atomics
  int chunk = (E + NBLK1 - 1) / NBLK1;
  k_l1hist  <<<NBLK1, 256, 0, stream>>>(dst, H, E, chunk);
  k_colscan <<<NB1,   256, 0, stream>>>(H, total);
  k_basescan<<<1,     256, 0, stream>>>(total, bucket_base, row_off, N);
  k_scatter1<<<NBLK1, 256, 0, stream>>>(src, dst, et, H, bucket_base, epk1, E, chunk);
  k_bucket  <<<NB1,   256, 0, stream>>>(epk1, bucket_base, epk, row_off, N);

  // ---- quantize input features to fp16 (slice-major)
  k_quant_s<<<(N * 16 + 255) / 256, 256, 0, stream>>>(features, xsA, N);

  // ---- 3 RGCN layers (fp16 slice-major activations ping-pong)
  ushort_t* bufs[2] = {xsA, xsB};
  int agg_grid = ((N + 15) / 16) * 4;   // x4 slices
  int gemm_grid = (N + 63) / 64;
  for (int l = 0; l < 3; ++l) {
    k_aggregate_s<<<agg_grid, 256, 0, stream>>>(bufs[l & 1], row_off, epk,
                                                comp[l], Zh, N);
    k_gemm_mfma<<<gemm_grid, 256, 0, stream>>>(Zh, bufs[l & 1], bases[l],
                                               loopw[l], biasp[l],
                                               bufs[(l + 1) & 1], N);
  }

  // ---- predictor + sigmoid (reads fp16 slice-major activations)
  k_pred<<<(N + 3) / 4, 256, 0, stream>>>(bufs[1], pred_w, pred_b, (float*)d_out, N);
}

// Round 9
// 481.648 us; speedup vs baseline: 1.0392x; 1.0392x over previous
//
#include <hip/hip_runtime.h>
#include <hip/hip_bf16.h>
#include <hip/hip_fp16.h>

// RGCN: 3 layers of basis-decomposed relational graph conv + predictor.
// CSR build via 2-level counting sort (NO global atomics).
// Activations stored HALF-MAJOR: xs2[2][N][32ch] fp16 -> each 32-channel
//   half-row is EXACTLY one 64B cache line (100% line efficiency), and each
//   half (6.4MB) is the working set of the XCDs that own it (half=blockIdx&1
//   rides the round-robin block->XCD dispatch: XCD j sees half j&1 only).
// k_aggregate_h: wave = 32ch x 2 edge-slots, one node per wave, 4 edges in
//   flight, shfl_xor(32) reduce. (R8 post-mortem: 16-ch slices had 50% line
//   efficiency + 4x epk decode -> regressed; 32-ch halves fix both.)
// k_gemm_mfma: out = relu([Z|x] @ [bases;loop_w] + bias) via
//   mfma_f32_16x16x32_f16, W^T fp16 + residual in LDS (~2^-22 weight error).
// Final: sigmoid(x @ pred_w + pred_b) from fp16.

#define NB1 196        // ceil(100000/512) coarse buckets
#define NBLK1 256      // L1 partition blocks
#define BUCKET_SHIFT 9 // 512 nodes per bucket
#define WT_LD 200      // padded k-stride (fp16) for W^T LDS: 400B = 2-way free

typedef unsigned short ushort_t;
typedef _Float16 h8 __attribute__((ext_vector_type(8)));
typedef float f32x4 __attribute__((ext_vector_type(4)));

__device__ inline ushort_t f2h(float f) {
  __half h = __float2half_rn(f);
  return *(ushort_t*)&h;
}
__device__ inline float h2f(ushort_t u) {
  __half h = *(__half*)&u;
  return __half2float(h);
}

// inclusive scan of one int per thread across a 256-thread block
__device__ inline int block_incl_scan_256(int v, int* wsums) {
  int lane = threadIdx.x & 63, wid = threadIdx.x >> 6;
  int s = v;
#pragma unroll
  for (int off = 1; off < 64; off <<= 1) {
    int u = __shfl_up(s, off, 64);
    if (lane >= off) s += u;
  }
  if (lane == 63) wsums[wid] = s;
  __syncthreads();
  if (threadIdx.x == 0) {
    int a = 0;
#pragma unroll
    for (int w = 0; w < 4; ++w) { int t = wsums[w]; wsums[w] = a; a += t; }
  }
  __syncthreads();
  return s + wsums[wid];
}

// ---- L1 pass a: per-block LDS histogram over 196 coarse buckets
__global__ void __launch_bounds__(256) k_l1hist(const int* __restrict__ dst,
                                                int* __restrict__ H, int E, int chunk) {
  __shared__ int h[NB1];
  int t = threadIdx.x;
  if (t < NB1) h[t] = 0;
  __syncthreads();
  int beg = blockIdx.x * chunk;
  int end = min(beg + chunk, E);
  for (int i = beg + t; i < end; i += 256) atomicAdd(&h[dst[i] >> BUCKET_SHIFT], 1);
  __syncthreads();
  if (t < NB1) H[blockIdx.x * NB1 + t] = h[t];
}

// ---- L1 pass b: scan each bucket's column of H -> excl offsets + totals
__global__ void __launch_bounds__(256) k_colscan(int* __restrict__ H,
                                                 int* __restrict__ total) {
  __shared__ int wsums[4];
  int b = blockIdx.x;
  int t = threadIdx.x;
  int v = H[t * NB1 + b];
  int s = block_incl_scan_256(v, wsums);
  H[t * NB1 + b] = s - v;
  if (t == 255) total[b] = s;
}

// ---- L1 pass c: scan bucket totals -> bucket_base
__global__ void __launch_bounds__(256) k_basescan(const int* __restrict__ total,
                                                  int* __restrict__ bucket_base,
                                                  int* __restrict__ row_off, int N) {
  __shared__ int wsums[4];
  int t = threadIdx.x;
  int v = (t < NB1) ? total[t] : 0;
  int s = block_incl_scan_256(v, wsums);
  if (t < NB1) bucket_base[t] = s - v;
  if (t == 255) { bucket_base[NB1] = s; row_off[N] = s; }
}

// ---- L1 pass d: scatter edges into bucket-partitioned epk1 via LDS cursors
__global__ void __launch_bounds__(256) k_scatter1(
    const int* __restrict__ src, const int* __restrict__ dst,
    const int* __restrict__ et, const int* __restrict__ H,
    const int* __restrict__ bucket_base, int* __restrict__ epk1,
    int E, int chunk) {
  __shared__ int cur[NB1];
  int t = threadIdx.x;
  if (t < NB1) cur[t] = bucket_base[t] + H[blockIdx.x * NB1 + t];
  __syncthreads();
  int beg = blockIdx.x * chunk;
  int end = min(beg + chunk, E);
  for (int i = beg + t; i < end; i += 256) {
    int d = dst[i];
    int b = d >> BUCKET_SHIFT;
    int p = atomicAdd(&cur[b], 1);
    epk1[p] = src[i] | (et[i] << 17) | ((d & 511) << 19);
  }
}

// ---- L2: per-bucket exact sort by dst_local (512 bins) -> epk + row_off
__global__ void __launch_bounds__(256) k_bucket(
    const int* __restrict__ epk1, const int* __restrict__ bucket_base,
    int* __restrict__ epk, int* __restrict__ row_off, int N) {
  __shared__ int hist[512];
  __shared__ int cur[512];
  __shared__ int wsums[4];
  int b = blockIdx.x;
  int t = threadIdx.x;
  int ebase = bucket_base[b], eend = bucket_base[b + 1];
  hist[t] = 0; hist[t + 256] = 0;
  __syncthreads();
  for (int i = ebase + t; i < eend; i += 256) atomicAdd(&hist[epk1[i] >> 19], 1);
  __syncthreads();
  int h0 = hist[2 * t], h1 = hist[2 * t + 1];
  int pair = h0 + h1;
  int incl = block_incl_scan_256(pair, wsums);
  int e0 = incl - pair;
  cur[2 * t] = ebase + e0;
  cur[2 * t + 1] = ebase + e0 + h0;
  int n0 = (b << BUCKET_SHIFT) + 2 * t;
  if (n0 < N) row_off[n0] = ebase + e0;
  if (n0 + 1 < N) row_off[n0 + 1] = ebase + e0 + h0;
  __syncthreads();
  for (int i = ebase + t; i < eend; i += 256) {
    int pk = epk1[i];
    int p = atomicAdd(&cur[pk >> 19], 1);
    epk[p] = pk;
  }
}

// ---- quantize fp32 -> fp16 (RTNE) into half-major layout xs2[2][N][32]
__global__ void __launch_bounds__(256) k_quant_h(const float* __restrict__ in,
                                                 ushort_t* __restrict__ out, int N) {
  int i = blockIdx.x * 256 + threadIdx.x;   // over N*16 float4 groups
  if (i >= N * 16) return;
  int node = i >> 4;
  int c0 = (i & 15) * 4;                    // channel 0..60
  float4 v = ((const float4*)in)[i];
  ushort4 q;
  q.x = f2h(v.x); q.y = f2h(v.y); q.z = f2h(v.z); q.w = f2h(v.w);
  *(ushort4*)(out + (size_t)(c0 >> 5) * N * 32 + (size_t)node * 32 + (c0 & 31)) = q;
}

// ---- half-sliced aggregate: half = blockIdx&1 (XCD j -> half j&1 only;
// 6.4MB working set vs 4MB L2). Wave = one node: 32ch x 2 edge-slots,
// 4 edges in flight (2-deep unroll per slot), shfl_xor(32) reduce.
__global__ void __launch_bounds__(256) k_aggregate_h(
    const ushort_t* __restrict__ xs2, const int* __restrict__ row_off,
    const int* __restrict__ epk, const float* __restrict__ comp,
    ushort_t* __restrict__ Zh, int N) {
  __shared__ float s_comp[8];
  if (threadIdx.x < 8) s_comp[threadIdx.x] = comp[threadIdx.x];
  __syncthreads();
  int half = blockIdx.x & 1;
  int wid = threadIdx.x >> 6, lane = threadIdx.x & 63;
  int s = lane >> 5, cl = lane & 31;
  const ushort_t* xsl = xs2 + (size_t)half * N * 32;
  int node = (blockIdx.x >> 1) * 4 + wid;
  if (node >= N) return;
  int beg = row_off[node], end = row_off[node + 1];
  float z0 = 0.f, z1 = 0.f;
  for (int e = beg; e < end; e += 4) {
    int ea = e + s, eb = e + 2 + s;
    int pka = epk[min(ea, end - 1)];
    int pkb = epk[min(eb, end - 1)];
    float ma = (ea < end) ? 1.f : 0.f;
    float mb = (eb < end) ? 1.f : 0.f;
    int sa = pka & 0x1FFFF, ra = (pka >> 17) & 3;
    int sb = pkb & 0x1FFFF, rb = (pkb >> 17) & 3;
    float xa = h2f(xsl[sa * 32 + cl]);   // 32 lanes x 2B = one 64B line
    float xb = h2f(xsl[sb * 32 + cl]);
    float ca0 = ma * s_comp[ra * 2 + 0], ca1 = ma * s_comp[ra * 2 + 1];
    float cb0 = mb * s_comp[rb * 2 + 0], cb1 = mb * s_comp[rb * 2 + 1];
    z0 = fmaf(ca0, xa, z0); z1 = fmaf(ca1, xa, z1);
    z0 = fmaf(cb0, xb, z0); z1 = fmaf(cb1, xb, z1);
  }
  // reduce over the 2 edge-slots; slot0 writes basis0, slot1 writes basis1
  z0 += __shfl_xor(z0, 32, 64);
  z1 += __shfl_xor(z1, 32, 64);
  if (s == 0) Zh[(size_t)node * 128 + half * 32 + cl] = f2h(z0);
  else        Zh[(size_t)node * 128 + 64 + half * 32 + cl] = f2h(z1);
}

// ---- MFMA GEMM: out = relu([Z | x](64x192 fp16) @ W(192x64) + bias)
// A-frags from global (rows read once); W^T fp16 + residual in LDS.
// Layouts (mfma_f32_16x16x32_f16): A row=l&15, k=8*(l>>4)+j;
// B k=8*(l>>4)+j, col=l&15; C/D col=l&15, row=4*(l>>4)+reg.
__global__ void __launch_bounds__(256) k_gemm_mfma(
    const ushort_t* __restrict__ Zh, const ushort_t* __restrict__ xs2,
    const float* __restrict__ bases, const float* __restrict__ loopw,
    const float* __restrict__ bias, ushort_t* __restrict__ xsOut, int N) {
  __shared__ ushort_t sWh[64 * WT_LD];  // W^T fp16:      25.6 KB
  __shared__ ushort_t sWr[64 * WT_LD];  // W^T residual:  25.6 KB
  int t = threadIdx.x;
  int w = t >> 6, l = t & 63;
  int lr = l & 15, lg = l >> 4;
  int row0 = blockIdx.x * 64 + w * 16;

  // ---- issue A-frag global loads FIRST (independent of LDS staging)
  int arow = row0 + lr;
  bool rok = arow < N;
  h8 a[6];
#pragma unroll
  for (int kb = 0; kb < 6; ++kb) {
    int k0 = kb * 32 + lg * 8;
    uint4 u = make_uint4(0, 0, 0, 0);
    if (rok) {
      if (kb < 4) u = *(const uint4*)(Zh + (size_t)arow * 128 + k0);
      else {
        int kk = k0 - 128;   // channel 0..63 -> half kk>>5, offset kk&31
        u = *(const uint4*)(xs2 + (size_t)(kk >> 5) * N * 32 +
                            (size_t)arow * 32 + (kk & 31));
      }
    }
    a[kb] = *(h8*)&u;
  }

  // ---- stage W^T as fp16 + residual (W = Wh + Wr exactly to ~2^-22)
#pragma unroll 4
  for (int i = 0; i < 48; ++i) {
    int idx = i * 256 + t;        // 0..12287
    int k = idx >> 6, c = idx & 63;
    float wv = (k < 128) ? bases[idx] : loopw[idx - 8192];
    ushort_t hh = f2h(wv);
    sWh[c * WT_LD + k] = hh;
    sWr[c * WT_LD + k] = f2h(wv - h2f(hh));
  }
  __syncthreads();

  // ---- MFMA: 4 col-tiles x 6 k-steps x (Wh + Wr)
  f32x4 acc[4];
#pragma unroll
  for (int c = 0; c < 4; ++c) acc[c] = (f32x4){0.f, 0.f, 0.f, 0.f};
#pragma unroll
  for (int c = 0; c < 4; ++c) {
    int col = c * 16 + lr;
    const ushort_t* bh = sWh + col * WT_LD + lg * 8;
    const ushort_t* br = sWr + col * WT_LD + lg * 8;
#pragma unroll
    for (int kb = 0; kb < 6; ++kb) {
      h8 vb = *(const h8*)(bh + kb * 32);
      acc[c] = __builtin_amdgcn_mfma_f32_16x16x32_f16(a[kb], vb, acc[c], 0, 0, 0);
      h8 vr = *(const h8*)(br + kb * 32);
      acc[c] = __builtin_amdgcn_mfma_f32_16x16x32_f16(a[kb], vr, acc[c], 0, 0, 0);
    }
  }

  // ---- epilogue: bias + relu -> fp16 half-major (col -> half c>>1)
#pragma unroll
  for (int c = 0; c < 4; ++c) {
    int col = c * 16 + lr;
    float bv = bias[col];
#pragma unroll
    for (int r = 0; r < 4; ++r) {
      int grow = row0 + lg * 4 + r;
      if (grow < N)
        xsOut[(size_t)(c >> 1) * N * 32 + (size_t)grow * 32 + (col & 31)] =
            f2h(fmaxf(acc[c][r] + bv, 0.f));
    }
  }
}

__global__ void __launch_bounds__(256) k_pred(
    const ushort_t* __restrict__ xs2, const float* __restrict__ pw,
    const float* __restrict__ pb, float* __restrict__ out, int N) {
  int node = blockIdx.x * 4 + (threadIdx.x >> 6);
  int lane = threadIdx.x & 63;
  if (node >= N) return;
  float v = h2f(xs2[(size_t)(lane >> 5) * N * 32 + (size_t)node * 32 + (lane & 31)])
            * pw[lane];
#pragma unroll
  for (int off = 32; off > 0; off >>= 1) v += __shfl_down(v, off, 64);
  if (lane == 0) {
    float logit = v + pb[0];
    out[node] = 1.f / (1.f + expf(-logit));
  }
}

extern "C" void kernel_launch(void* const* d_in, const int* in_sizes, int n_in,
                              void* d_out, int out_size, void* d_ws, size_t ws_size,
                              hipStream_t stream) {
  const float* features = (const float*)d_in[0];
  const int* src = (const int*)d_in[1];
  const int* dst = (const int*)d_in[2];
  const int* et  = (const int*)d_in[3];
  const float* bases[3] = {(const float*)d_in[4], (const float*)d_in[8],  (const float*)d_in[12]};
  const float* comp[3]  = {(const float*)d_in[5], (const float*)d_in[9],  (const float*)d_in[13]};
  const float* loopw[3] = {(const float*)d_in[6], (const float*)d_in[10], (const float*)d_in[14]};
  const float* biasp[3] = {(const float*)d_in[7], (const float*)d_in[11], (const float*)d_in[15]};
  const float* pred_w = (const float*)d_in[16];
  const float* pred_b = (const float*)d_in[17];

  const int N = in_sizes[0] / 64;   // 100000
  const int E = in_sizes[1];        // 1600000

  char* ws = (char*)d_ws;
  size_t off = 0;
  auto take = [&](size_t bytes) {
    char* p = ws + off;
    off += (bytes + 255) & ~(size_t)255;
    return p;
  };
  int*      row_off     = (int*)     take((size_t)(N + 1) * 4);
  int*      H           = (int*)     take((size_t)NBLK1 * NB1 * 4);
  int*      total       = (int*)     take((size_t)NB1 * 4);
  int*      bucket_base = (int*)     take((size_t)(NB1 + 1) * 4);
  int*      epk         = (int*)     take((size_t)(E + 8) * 4);  // +pad
  ushort_t* Zh          = (ushort_t*)take((size_t)N * 128 * 2);
  ushort_t* xsA         = (ushort_t*)take((size_t)N * 64 * 2);
  ushort_t* xsB         = (ushort_t*)take((size_t)N * 64 * 2);
  int*      epk1        = (int*)Zh;   // alias: Zh dead during CSR build
  (void)ws_size;

  // ---- CSR build: 2-level counting sort, no global atomics
  int chunk = (E + NBLK1 - 1) / NBLK1;
  k_l1hist  <<<NBLK1, 256, 0, stream>>>(dst, H, E, chunk);
  k_colscan <<<NB1,   256, 0, stream>>>(H, total);
  k_basescan<<<1,     256, 0, stream>>>(total, bucket_base, row_off, N);
  k_scatter1<<<NBLK1, 256, 0, stream>>>(src, dst, et, H, bucket_base, epk1, E, chunk);
  k_bucket  <<<NB1,   256, 0, stream>>>(epk1, bucket_base, epk, row_off, N);

  // ---- quantize input features to fp16 (half-major)
  k_quant_h<<<(N * 16 + 255) / 256, 256, 0, stream>>>(features, xsA, N);

  // ---- 3 RGCN layers (fp16 half-major activations ping-pong)
  ushort_t* bufs[2] = {xsA, xsB};
  int agg_grid = ((N + 3) / 4) * 2;   // x2 halves
  int gemm_grid = (N + 63) / 64;
  for (int l = 0; l < 3; ++l) {
    k_aggregate_h<<<agg_grid, 256, 0, stream>>>(bufs[l & 1], row_off, epk,
                                                comp[l], Zh, N);
    k_gemm_mfma<<<gemm_grid, 256, 0, stream>>>(Zh, bufs[l & 1], bases[l],
                                               loopw[l], biasp[l],
                                               bufs[(l + 1) & 1], N);
  }

  // ---- predictor + sigmoid (reads fp16 half-major activations)
  k_pred<<<(N + 3) / 4, 256, 0, stream>>>(bufs[1], pred_w, pred_b, (float*)d_out, N);
}

// Round 10
// 420.848 us; speedup vs baseline: 1.1894x; 1.1445x over previous
//
#include <hip/hip_runtime.h>
#include <hip/hip_bf16.h>
#include <hip/hip_fp16.h>

// RGCN: 3 layers of basis-decomposed relational graph conv + predictor.
// CSR build via 2-level counting sort (NO global atomics); k_bucket caches
//   its bucket's edges in LDS (single global read of epk1).
// k_aggregate: wave/node fp16 row-major gather (structural ~68us: ~205MB
//   logical random gather, ~60% L2 hit = capacity ratio, MLP cap saturated;
//   R6 unroll null, R8/R9 XCD-slicing falsified).
// k_prepw: one-time W^T fp16 + residual (W = Wh + Wr -> ~2^-22 weight err).
// k_gemm_mfma: out = relu([Z|x] @ [bases;loop_w] + bias) via
//   mfma_f32_16x16x32_f16; A-frags AND B-frags straight from global
//   (B is 48KB/layer, L1/L2-hot) -> no LDS, no syncthreads, max occupancy.
// Final: sigmoid(x @ pred_w + pred_b) from fp16.

#define NB1 196        // ceil(100000/512) coarse buckets
#define NBLK1 256      // L1 partition blocks
#define BUCKET_SHIFT 9 // 512 nodes per bucket
#define CAP_BUCKET 12288  // LDS edge-cache capacity (mean 8192, 45-sigma pad)

typedef unsigned short ushort_t;
typedef _Float16 h8 __attribute__((ext_vector_type(8)));
typedef float f32x4 __attribute__((ext_vector_type(4)));

__device__ inline ushort_t f2h(float f) {
  __half h = __float2half_rn(f);
  return *(ushort_t*)&h;
}
__device__ inline float h2f(ushort_t u) {
  __half h = *(__half*)&u;
  return __half2float(h);
}

// inclusive scan of one int per thread across a 256-thread block
__device__ inline int block_incl_scan_256(int v, int* wsums) {
  int lane = threadIdx.x & 63, wid = threadIdx.x >> 6;
  int s = v;
#pragma unroll
  for (int off = 1; off < 64; off <<= 1) {
    int u = __shfl_up(s, off, 64);
    if (lane >= off) s += u;
  }
  if (lane == 63) wsums[wid] = s;
  __syncthreads();
  if (threadIdx.x == 0) {
    int a = 0;
#pragma unroll
    for (int w = 0; w < 4; ++w) { int t = wsums[w]; wsums[w] = a; a += t; }
  }
  __syncthreads();
  return s + wsums[wid];
}

// ---- L1 pass a: per-block LDS histogram over 196 coarse buckets
__global__ void __launch_bounds__(256) k_l1hist(const int* __restrict__ dst,
                                                int* __restrict__ H, int E, int chunk) {
  __shared__ int h[NB1];
  int t = threadIdx.x;
  if (t < NB1) h[t] = 0;
  __syncthreads();
  int beg = blockIdx.x * chunk;
  int end = min(beg + chunk, E);
  for (int i = beg + t; i < end; i += 256) atomicAdd(&h[dst[i] >> BUCKET_SHIFT], 1);
  __syncthreads();
  if (t < NB1) H[blockIdx.x * NB1 + t] = h[t];
}

// ---- L1 pass b: scan each bucket's column of H -> excl offsets + totals
__global__ void __launch_bounds__(256) k_colscan(int* __restrict__ H,
                                                 int* __restrict__ total) {
  __shared__ int wsums[4];
  int b = blockIdx.x;
  int t = threadIdx.x;
  int v = H[t * NB1 + b];
  int s = block_incl_scan_256(v, wsums);
  H[t * NB1 + b] = s - v;
  if (t == 255) total[b] = s;
}

// ---- L1 pass c: scan bucket totals -> bucket_base
__global__ void __launch_bounds__(256) k_basescan(const int* __restrict__ total,
                                                  int* __restrict__ bucket_base,
                                                  int* __restrict__ row_off, int N) {
  __shared__ int wsums[4];
  int t = threadIdx.x;
  int v = (t < NB1) ? total[t] : 0;
  int s = block_incl_scan_256(v, wsums);
  if (t < NB1) bucket_base[t] = s - v;
  if (t == 255) { bucket_base[NB1] = s; row_off[N] = s; }
}

// ---- L1 pass d: scatter edges into bucket-partitioned epk1 via LDS cursors
__global__ void __launch_bounds__(256) k_scatter1(
    const int* __restrict__ src, const int* __restrict__ dst,
    const int* __restrict__ et, const int* __restrict__ H,
    const int* __restrict__ bucket_base, int* __restrict__ epk1,
    int E, int chunk) {
  __shared__ int cur[NB1];
  int t = threadIdx.x;
  if (t < NB1) cur[t] = bucket_base[t] + H[blockIdx.x * NB1 + t];
  __syncthreads();
  int beg = blockIdx.x * chunk;
  int end = min(beg + chunk, E);
  for (int i = beg + t; i < end; i += 256) {
    int d = dst[i];
    int b = d >> BUCKET_SHIFT;
    int p = atomicAdd(&cur[b], 1);
    epk1[p] = src[i] | (et[i] << 17) | ((d & 511) << 19);
  }
}

// ---- L2: per-bucket exact sort by dst_local (512 bins) -> epk + row_off.
// Bucket's edges cached in LDS: epk1 read ONCE; scatter pass reads LDS.
__global__ void __launch_bounds__(256) k_bucket(
    const int* __restrict__ epk1, const int* __restrict__ bucket_base,
    int* __restrict__ epk, int* __restrict__ row_off, int N) {
  __shared__ int eC[CAP_BUCKET];   // 48 KB edge cache
  __shared__ int hist[512];
  __shared__ int cur[512];
  __shared__ int wsums[4];
  int b = blockIdx.x;
  int t = threadIdx.x;
  int ebase = bucket_base[b], eend = bucket_base[b + 1];
  int cnt = eend - ebase;
  bool fit = (cnt <= CAP_BUCKET);
  hist[t] = 0; hist[t + 256] = 0;
  __syncthreads();
  if (fit) {
    for (int i = t; i < cnt; i += 256) {
      int pk = epk1[ebase + i];
      eC[i] = pk;
      atomicAdd(&hist[pk >> 19], 1);
    }
  } else {  // safety fallback (statistically unreachable at mean 8192)
    for (int i = ebase + t; i < eend; i += 256) atomicAdd(&hist[epk1[i] >> 19], 1);
  }
  __syncthreads();
  int h0 = hist[2 * t], h1 = hist[2 * t + 1];
  int pair = h0 + h1;
  int incl = block_incl_scan_256(pair, wsums);
  int e0 = incl - pair;
  cur[2 * t] = ebase + e0;
  cur[2 * t + 1] = ebase + e0 + h0;
  int n0 = (b << BUCKET_SHIFT) + 2 * t;
  if (n0 < N) row_off[n0] = ebase + e0;
  if (n0 + 1 < N) row_off[n0 + 1] = ebase + e0 + h0;
  __syncthreads();
  if (fit) {
    for (int i = t; i < cnt; i += 256) {
      int pk = eC[i];
      int p = atomicAdd(&cur[pk >> 19], 1);
      epk[p] = pk;
    }
  } else {
    for (int i = ebase + t; i < eend; i += 256) {
      int pk = epk1[i];
      int p = atomicAdd(&cur[pk >> 19], 1);
      epk[p] = pk;
    }
  }
}

// ---- quantize fp32 -> fp16 (RTNE), vectorized, row-major
__global__ void __launch_bounds__(256) k_quant(const float* __restrict__ in,
                                               ushort_t* __restrict__ out, int n4) {
  int i = blockIdx.x * blockDim.x + threadIdx.x;
  if (i < n4) {
    float4 v = ((const float4*)in)[i];
    ushort4 q;
    q.x = f2h(v.x); q.y = f2h(v.y);
    q.z = f2h(v.z); q.w = f2h(v.w);
    ((ushort4*)out)[i] = q;
  }
}

// ---- one-time W^T staging: WhT/WrT [3][64 cols][192 k] fp16
__global__ void __launch_bounds__(256) k_prepw(
    const float* __restrict__ b1, const float* __restrict__ lw1,
    const float* __restrict__ b2, const float* __restrict__ lw2,
    const float* __restrict__ b3, const float* __restrict__ lw3,
    ushort_t* __restrict__ WhT, ushort_t* __restrict__ WrT) {
  int i = blockIdx.x * 256 + threadIdx.x;
  if (i >= 3 * 12288) return;
  int l = i / 12288, idx = i - l * 12288;
  int k = idx >> 6, c = idx & 63;
  const float* B = (l == 0) ? b1 : (l == 1) ? b2 : b3;
  const float* L = (l == 0) ? lw1 : (l == 1) ? lw2 : lw3;
  float wv = (k < 128) ? B[idx] : L[idx - 8192];
  ushort_t hh = f2h(wv);
  size_t o = (size_t)l * 12288 + (size_t)c * 192 + k;
  WhT[o] = hh;
  WrT[o] = f2h(wv - h2f(hh));
}

// One wave per node; lane = channel. fp16 gather (128B/edge row), 8-deep
// unroll. Emits Z as fp16: Zh[node][0..63]=basis0, [64..127]=basis1.
__global__ void __launch_bounds__(256) k_aggregate(
    const ushort_t* __restrict__ xq, const int* __restrict__ row_off,
    const int* __restrict__ epk, const float* __restrict__ comp,
    ushort_t* __restrict__ Zh, int N) {
  __shared__ float s_comp[8];
  if (threadIdx.x < 8) s_comp[threadIdx.x] = comp[threadIdx.x];
  __syncthreads();
  int node = blockIdx.x * 4 + (threadIdx.x >> 6);
  int lane = threadIdx.x & 63;
  if (node >= N) return;
  int beg = row_off[node], end = row_off[node + 1];
  float z0 = 0.f, z1 = 0.f;
  int e = beg;
  for (; e + 7 < end; e += 8) {
    int pk[8];
    float xv[8];
#pragma unroll
    for (int u = 0; u < 8; ++u) pk[u] = epk[e + u];
#pragma unroll
    for (int u = 0; u < 8; ++u)
      xv[u] = h2f(xq[(size_t)(pk[u] & 0x1FFFF) * 64 + lane]);
#pragma unroll
    for (int u = 0; u < 8; ++u) {
      int r = (pk[u] >> 17) & 3;
      z0 = fmaf(s_comp[r * 2 + 0], xv[u], z0);
      z1 = fmaf(s_comp[r * 2 + 1], xv[u], z1);
    }
  }
  for (; e < end; ++e) {
    int pk = epk[e];
    int s = pk & 0x1FFFF, r = (pk >> 17) & 3;
    float xv = h2f(xq[(size_t)s * 64 + lane]);
    z0 = fmaf(s_comp[r * 2 + 0], xv, z0);
    z1 = fmaf(s_comp[r * 2 + 1], xv, z1);
  }
  Zh[(size_t)node * 128 + lane] = f2h(z0);
  Zh[(size_t)node * 128 + 64 + lane] = f2h(z1);
}

// ---- MFMA GEMM, LDS-free: out = relu([Z|x](64x192 fp16) @ W + bias).
// A-frags from global (rows read once); B-frags from global WhT/WrT
// (48KB/layer, shared by all blocks -> L1/L2-hot).
// Layouts (mfma_f32_16x16x32_f16): A row=l&15, k=8*(l>>4)+j;
// B k=8*(l>>4)+j, col=l&15; C/D col=l&15, row=4*(l>>4)+reg.
__global__ void __launch_bounds__(256) k_gemm_mfma(
    const ushort_t* __restrict__ Zh, const ushort_t* __restrict__ xq,
    const ushort_t* __restrict__ WhT, const ushort_t* __restrict__ WrT,
    const float* __restrict__ bias, ushort_t* __restrict__ xqOut, int N) {
  int t = threadIdx.x;
  int w = t >> 6, l = t & 63;
  int lr = l & 15, lg = l >> 4;
  int row0 = blockIdx.x * 64 + w * 16;

  int arow = row0 + lr;
  bool rok = arow < N;
  h8 a[6];
#pragma unroll
  for (int kb = 0; kb < 6; ++kb) {
    int k0 = kb * 32 + lg * 8;
    uint4 u = make_uint4(0, 0, 0, 0);
    if (rok) {
      if (kb < 4) u = *(const uint4*)(Zh + (size_t)arow * 128 + k0);
      else        u = *(const uint4*)(xq + (size_t)arow * 64 + (k0 - 128));
    }
    a[kb] = *(h8*)&u;
  }

  f32x4 acc[4];
#pragma unroll
  for (int c = 0; c < 4; ++c) acc[c] = (f32x4){0.f, 0.f, 0.f, 0.f};
#pragma unroll
  for (int c = 0; c < 4; ++c) {
    int col = c * 16 + lr;
    const ushort_t* bh = WhT + (size_t)col * 192 + lg * 8;
    const ushort_t* br = WrT + (size_t)col * 192 + lg * 8;
#pragma unroll
    for (int kb = 0; kb < 6; ++kb) {
      h8 vb = *(const h8*)(bh + kb * 32);
      acc[c] = __builtin_amdgcn_mfma_f32_16x16x32_f16(a[kb], vb, acc[c], 0, 0, 0);
      h8 vr = *(const h8*)(br + kb * 32);
      acc[c] = __builtin_amdgcn_mfma_f32_16x16x32_f16(a[kb], vr, acc[c], 0, 0, 0);
    }
  }

  // ---- epilogue: bias + relu -> fp16 activations
#pragma unroll
  for (int c = 0; c < 4; ++c) {
    int col = c * 16 + lr;
    float bv = bias[col];
#pragma unroll
    for (int r = 0; r < 4; ++r) {
      int grow = row0 + lg * 4 + r;
      if (grow < N)
        xqOut[(size_t)grow * 64 + col] = f2h(fmaxf(acc[c][r] + bv, 0.f));
    }
  }
}

__global__ void __launch_bounds__(256) k_pred(
    const ushort_t* __restrict__ x, const float* __restrict__ pw,
    const float* __restrict__ pb, float* __restrict__ out, int N) {
  int node = blockIdx.x * 4 + (threadIdx.x >> 6);
  int lane = threadIdx.x & 63;
  if (node >= N) return;
  float v = h2f(x[(size_t)node * 64 + lane]) * pw[lane];
#pragma unroll
  for (int off = 32; off > 0; off >>= 1) v += __shfl_down(v, off, 64);
  if (lane == 0) {
    float logit = v + pb[0];
    out[node] = 1.f / (1.f + expf(-logit));
  }
}

extern "C" void kernel_launch(void* const* d_in, const int* in_sizes, int n_in,
                              void* d_out, int out_size, void* d_ws, size_t ws_size,
                              hipStream_t stream) {
  const float* features = (const float*)d_in[0];
  const int* src = (const int*)d_in[1];
  const int* dst = (const int*)d_in[2];
  const int* et  = (const int*)d_in[3];
  const float* bases[3] = {(const float*)d_in[4], (const float*)d_in[8],  (const float*)d_in[12]};
  const float* comp[3]  = {(const float*)d_in[5], (const float*)d_in[9],  (const float*)d_in[13]};
  const float* loopw[3] = {(const float*)d_in[6], (const float*)d_in[10], (const float*)d_in[14]};
  const float* biasp[3] = {(const float*)d_in[7], (const float*)d_in[11], (const float*)d_in[15]};
  const float* pred_w = (const float*)d_in[16];
  const float* pred_b = (const float*)d_in[17];

  const int N = in_sizes[0] / 64;   // 100000
  const int E = in_sizes[1];        // 1600000

  char* ws = (char*)d_ws;
  size_t off = 0;
  auto take = [&](size_t bytes) {
    char* p = ws + off;
    off += (bytes + 255) & ~(size_t)255;
    return p;
  };
  int*      row_off     = (int*)     take((size_t)(N + 1) * 4);
  int*      H           = (int*)     take((size_t)NBLK1 * NB1 * 4);
  int*      total       = (int*)     take((size_t)NB1 * 4);
  int*      bucket_base = (int*)     take((size_t)(NB1 + 1) * 4);
  int*      epk         = (int*)     take((size_t)(E + 8) * 4);  // +pad
  ushort_t* Zh          = (ushort_t*)take((size_t)N * 128 * 2);
  ushort_t* xqA         = (ushort_t*)take((size_t)N * 64 * 2);
  ushort_t* xqB         = (ushort_t*)take((size_t)N * 64 * 2);
  ushort_t* WhT         = (ushort_t*)take((size_t)3 * 12288 * 2);
  ushort_t* WrT         = (ushort_t*)take((size_t)3 * 12288 * 2);
  int*      epk1        = (int*)Zh;   // alias: Zh dead during CSR build
  (void)ws_size;

  // ---- CSR build: 2-level counting sort, no global atomics
  int chunk = (E + NBLK1 - 1) / NBLK1;
  k_l1hist  <<<NBLK1, 256, 0, stream>>>(dst, H, E, chunk);
  k_colscan <<<NB1,   256, 0, stream>>>(H, total);
  k_basescan<<<1,     256, 0, stream>>>(total, bucket_base, row_off, N);
  k_scatter1<<<NBLK1, 256, 0, stream>>>(src, dst, et, H, bucket_base, epk1, E, chunk);
  k_bucket  <<<NB1,   256, 0, stream>>>(epk1, bucket_base, epk, row_off, N);

  // ---- quantize input features to fp16; stage W^T fp16+residual (once)
  k_quant<<<(N * 16 + 255) / 256, 256, 0, stream>>>(features, xqA, N * 16);
  k_prepw<<<(3 * 12288 + 255) / 256, 256, 0, stream>>>(
      bases[0], loopw[0], bases[1], loopw[1], bases[2], loopw[2], WhT, WrT);

  // ---- 3 RGCN layers (fp16 activations ping-pong)
  ushort_t* bufs[2] = {xqA, xqB};
  int agg_grid = (N + 3) / 4;
  int gemm_grid = (N + 63) / 64;
  for (int l = 0; l < 3; ++l) {
    k_aggregate<<<agg_grid, 256, 0, stream>>>(bufs[l & 1], row_off, epk,
                                              comp[l], Zh, N);
    k_gemm_mfma<<<gemm_grid, 256, 0, stream>>>(Zh, bufs[l & 1],
                                               WhT + (size_t)l * 12288,
                                               WrT + (size_t)l * 12288,
                                               biasp[l], bufs[(l + 1) & 1], N);
  }

  // ---- predictor + sigmoid (reads fp16 activations)
  k_pred<<<(N + 3) / 4, 256, 0, stream>>>(bufs[1], pred_w, pred_b, (float*)d_out, N);
}

// Round 11
// 362.509 us; speedup vs baseline: 1.3808x; 1.1609x over previous
//
#include <hip/hip_runtime.h>
#include <hip/hip_bf16.h>
#include <hip/hip_fp16.h>

// RGCN: 3 layers of basis-decomposed relational graph conv + predictor.
// CSR build via 2-level counting sort (NO global atomics).
// k_aggregate: wave/node fp16 gather (structural ~68us: ~205MB logical
//   random gather, ~60% L2 hit = capacity ratio, MLP cap saturated).
//   epk loads + Zh stores NONTEMPORAL to keep streaming traffic from
//   evicting the gather's xq working set (R11 experiment).
// k_gemm_mfma: out = relu([Z|x] @ [bases;loop_w] + bias) via
//   mfma_f32_16x16x32_f16; W^T fp16 + residual staged in LDS (R7 form —
//   R10's global-B variant was uncoalesced/L1-thrashing, +70us. reverted).
//   Last layer fuses the predictor: sigmoid(out @ pred_w + pred_b) via
//   16-lane shfl reduce straight from fp32 accumulators.

#define NB1 196        // ceil(100000/512) coarse buckets
#define NBLK1 256      // L1 partition blocks
#define BUCKET_SHIFT 9 // 512 nodes per bucket
#define WT_LD 200      // padded k-stride (fp16) for W^T LDS: 400B = 2-way free

typedef unsigned short ushort_t;
typedef _Float16 h8 __attribute__((ext_vector_type(8)));
typedef float f32x4 __attribute__((ext_vector_type(4)));
typedef unsigned int u32x4 __attribute__((ext_vector_type(4)));

__device__ inline ushort_t f2h(float f) {
  __half h = __float2half_rn(f);
  return *(ushort_t*)&h;
}
__device__ inline float h2f(ushort_t u) {
  __half h = *(__half*)&u;
  return __half2float(h);
}

// inclusive scan of one int per thread across a 256-thread block
__device__ inline int block_incl_scan_256(int v, int* wsums) {
  int lane = threadIdx.x & 63, wid = threadIdx.x >> 6;
  int s = v;
#pragma unroll
  for (int off = 1; off < 64; off <<= 1) {
    int u = __shfl_up(s, off, 64);
    if (lane >= off) s += u;
  }
  if (lane == 63) wsums[wid] = s;
  __syncthreads();
  if (threadIdx.x == 0) {
    int a = 0;
#pragma unroll
    for (int w = 0; w < 4; ++w) { int t = wsums[w]; wsums[w] = a; a += t; }
  }
  __syncthreads();
  return s + wsums[wid];
}

// ---- L1 pass a: per-block LDS histogram over 196 coarse buckets
__global__ void __launch_bounds__(256) k_l1hist(const int* __restrict__ dst,
                                                int* __restrict__ H, int E, int chunk) {
  __shared__ int h[NB1];
  int t = threadIdx.x;
  if (t < NB1) h[t] = 0;
  __syncthreads();
  int beg = blockIdx.x * chunk;
  int end = min(beg + chunk, E);
  for (int i = beg + t; i < end; i += 256) atomicAdd(&h[dst[i] >> BUCKET_SHIFT], 1);
  __syncthreads();
  if (t < NB1) H[blockIdx.x * NB1 + t] = h[t];
}

// ---- L1 pass b: scan each bucket's column of H -> excl offsets + totals
__global__ void __launch_bounds__(256) k_colscan(int* __restrict__ H,
                                                 int* __restrict__ total) {
  __shared__ int wsums[4];
  int b = blockIdx.x;
  int t = threadIdx.x;
  int v = H[t * NB1 + b];
  int s = block_incl_scan_256(v, wsums);
  H[t * NB1 + b] = s - v;
  if (t == 255) total[b] = s;
}

// ---- L1 pass c: scan bucket totals -> bucket_base
__global__ void __launch_bounds__(256) k_basescan(const int* __restrict__ total,
                                                  int* __restrict__ bucket_base,
                                                  int* __restrict__ row_off, int N) {
  __shared__ int wsums[4];
  int t = threadIdx.x;
  int v = (t < NB1) ? total[t] : 0;
  int s = block_incl_scan_256(v, wsums);
  if (t < NB1) bucket_base[t] = s - v;
  if (t == 255) { bucket_base[NB1] = s; row_off[N] = s; }
}

// ---- L1 pass d: scatter edges into bucket-partitioned epk1 via LDS cursors
__global__ void __launch_bounds__(256) k_scatter1(
    const int* __restrict__ src, const int* __restrict__ dst,
    const int* __restrict__ et, const int* __restrict__ H,
    const int* __restrict__ bucket_base, int* __restrict__ epk1,
    int E, int chunk) {
  __shared__ int cur[NB1];
  int t = threadIdx.x;
  if (t < NB1) cur[t] = bucket_base[t] + H[blockIdx.x * NB1 + t];
  __syncthreads();
  int beg = blockIdx.x * chunk;
  int end = min(beg + chunk, E);
  for (int i = beg + t; i < end; i += 256) {
    int d = dst[i];
    int b = d >> BUCKET_SHIFT;
    int p = atomicAdd(&cur[b], 1);
    epk1[p] = src[i] | (et[i] << 17) | ((d & 511) << 19);
  }
}

// ---- L2: per-bucket exact sort by dst_local (512 bins) -> epk + row_off
__global__ void __launch_bounds__(256) k_bucket(
    const int* __restrict__ epk1, const int* __restrict__ bucket_base,
    int* __restrict__ epk, int* __restrict__ row_off, int N) {
  __shared__ int hist[512];
  __shared__ int cur[512];
  __shared__ int wsums[4];
  int b = blockIdx.x;
  int t = threadIdx.x;
  int ebase = bucket_base[b], eend = bucket_base[b + 1];
  hist[t] = 0; hist[t + 256] = 0;
  __syncthreads();
  for (int i = ebase + t; i < eend; i += 256) atomicAdd(&hist[epk1[i] >> 19], 1);
  __syncthreads();
  int h0 = hist[2 * t], h1 = hist[2 * t + 1];
  int pair = h0 + h1;
  int incl = block_incl_scan_256(pair, wsums);
  int e0 = incl - pair;
  cur[2 * t] = ebase + e0;
  cur[2 * t + 1] = ebase + e0 + h0;
  int n0 = (b << BUCKET_SHIFT) + 2 * t;
  if (n0 < N) row_off[n0] = ebase + e0;
  if (n0 + 1 < N) row_off[n0 + 1] = ebase + e0 + h0;
  __syncthreads();
  for (int i = ebase + t; i < eend; i += 256) {
    int pk = epk1[i];
    int p = atomicAdd(&cur[pk >> 19], 1);
    epk[p] = pk;
  }
}

// ---- quantize fp32 -> fp16 (RTNE), vectorized
__global__ void __launch_bounds__(256) k_quant(const float* __restrict__ in,
                                               ushort_t* __restrict__ out, int n4) {
  int i = blockIdx.x * blockDim.x + threadIdx.x;
  if (i < n4) {
    float4 v = ((const float4*)in)[i];
    ushort4 q;
    q.x = f2h(v.x); q.y = f2h(v.y);
    q.z = f2h(v.z); q.w = f2h(v.w);
    ((ushort4*)out)[i] = q;
  }
}

// One wave per node; lane = channel. fp16 gather (128B/edge row), 8-deep
// unroll. epk loads + Zh stores nontemporal (keep L2 for the xq gather).
__global__ void __launch_bounds__(256) k_aggregate(
    const ushort_t* __restrict__ xq, const int* __restrict__ row_off,
    const int* __restrict__ epk, const float* __restrict__ comp,
    ushort_t* __restrict__ Zh, int N) {
  __shared__ float s_comp[8];
  if (threadIdx.x < 8) s_comp[threadIdx.x] = comp[threadIdx.x];
  __syncthreads();
  int node = blockIdx.x * 4 + (threadIdx.x >> 6);
  int lane = threadIdx.x & 63;
  if (node >= N) return;
  int beg = row_off[node], end = row_off[node + 1];
  float z0 = 0.f, z1 = 0.f;
  int e = beg;
  for (; e + 7 < end; e += 8) {
    int pk[8];
    float xv[8];
#pragma unroll
    for (int u = 0; u < 8; ++u) pk[u] = __builtin_nontemporal_load(&epk[e + u]);
#pragma unroll
    for (int u = 0; u < 8; ++u)
      xv[u] = h2f(xq[(size_t)(pk[u] & 0x1FFFF) * 64 + lane]);
#pragma unroll
    for (int u = 0; u < 8; ++u) {
      int r = (pk[u] >> 17) & 3;
      z0 = fmaf(s_comp[r * 2 + 0], xv[u], z0);
      z1 = fmaf(s_comp[r * 2 + 1], xv[u], z1);
    }
  }
  for (; e < end; ++e) {
    int pk = epk[e];
    int s = pk & 0x1FFFF, r = (pk >> 17) & 3;
    float xv = h2f(xq[(size_t)s * 64 + lane]);
    z0 = fmaf(s_comp[r * 2 + 0], xv, z0);
    z1 = fmaf(s_comp[r * 2 + 1], xv, z1);
  }
  __builtin_nontemporal_store(f2h(z0), &Zh[(size_t)node * 128 + lane]);
  __builtin_nontemporal_store(f2h(z1), &Zh[(size_t)node * 128 + 64 + lane]);
}

// ---- MFMA GEMM: out = relu([Z | x](64x192 fp16) @ W(192x64) + bias)
// A-frags from global nontemporal (rows read once); W^T fp16 + residual in
// LDS. Optional fused predictor (last layer): sigmoid(out @ pw + pb).
// Layouts (mfma_f32_16x16x32_f16): A row=l&15, k=8*(l>>4)+j;
// B k=8*(l>>4)+j, col=l&15; C/D col=l&15, row=4*(l>>4)+reg.
__global__ void __launch_bounds__(256) k_gemm_mfma(
    const ushort_t* __restrict__ Zh, const ushort_t* __restrict__ xq,
    const float* __restrict__ bases, const float* __restrict__ loopw,
    const float* __restrict__ bias, ushort_t* __restrict__ xqOut,
    const float* __restrict__ pw, const float* __restrict__ pb,
    float* __restrict__ predOut, int N) {
  __shared__ ushort_t sWh[64 * WT_LD];  // W^T fp16:      25.6 KB
  __shared__ ushort_t sWr[64 * WT_LD];  // W^T residual:  25.6 KB
  int t = threadIdx.x;
  int w = t >> 6, l = t & 63;
  int lr = l & 15, lg = l >> 4;
  int row0 = blockIdx.x * 64 + w * 16;

  // ---- issue A-frag global loads FIRST (independent of LDS staging)
  int arow = row0 + lr;
  bool rok = arow < N;
  h8 a[6];
#pragma unroll
  for (int kb = 0; kb < 6; ++kb) {
    int k0 = kb * 32 + lg * 8;
    u32x4 u = (u32x4){0, 0, 0, 0};
    if (rok) {
      if (kb < 4)
        u = __builtin_nontemporal_load(
            (const u32x4*)(Zh + (size_t)arow * 128 + k0));
      else
        u = __builtin_nontemporal_load(
            (const u32x4*)(xq + (size_t)arow * 64 + (k0 - 128)));
    }
    a[kb] = *(h8*)&u;
  }

  // ---- stage W^T as fp16 + residual (W = Wh + Wr exactly to ~2^-22)
#pragma unroll 4
  for (int i = 0; i < 48; ++i) {
    int idx = i * 256 + t;        // 0..12287
    int k = idx >> 6, c = idx & 63;
    float wv = (k < 128) ? bases[idx] : loopw[idx - 8192];
    ushort_t hh = f2h(wv);
    sWh[c * WT_LD + k] = hh;
    sWr[c * WT_LD + k] = f2h(wv - h2f(hh));
  }
  __syncthreads();

  // ---- MFMA: 4 col-tiles x 6 k-steps x (Wh + Wr)
  f32x4 acc[4];
#pragma unroll
  for (int c = 0; c < 4; ++c) acc[c] = (f32x4){0.f, 0.f, 0.f, 0.f};
#pragma unroll
  for (int c = 0; c < 4; ++c) {
    int col = c * 16 + lr;
    const ushort_t* bh = sWh + col * WT_LD + lg * 8;
    const ushort_t* br = sWr + col * WT_LD + lg * 8;
#pragma unroll
    for (int kb = 0; kb < 6; ++kb) {
      h8 vb = *(const h8*)(bh + kb * 32);
      acc[c] = __builtin_amdgcn_mfma_f32_16x16x32_f16(a[kb], vb, acc[c], 0, 0, 0);
      h8 vr = *(const h8*)(br + kb * 32);
      acc[c] = __builtin_amdgcn_mfma_f32_16x16x32_f16(a[kb], vr, acc[c], 0, 0, 0);
    }
  }

  // ---- epilogue: bias + relu
  float o_[4][4];
#pragma unroll
  for (int c = 0; c < 4; ++c) {
    float bv = bias[c * 16 + lr];
#pragma unroll
    for (int r = 0; r < 4; ++r) o_[c][r] = fmaxf(acc[c][r] + bv, 0.f);
  }
  if (xqOut) {
#pragma unroll
    for (int c = 0; c < 4; ++c) {
      int col = c * 16 + lr;
#pragma unroll
      for (int r = 0; r < 4; ++r) {
        int grow = row0 + lg * 4 + r;
        if (grow < N)
          xqOut[(size_t)grow * 64 + col] = f2h(o_[c][r]);
      }
    }
  }
  if (predOut) {
    // fused predictor: per row, dot(out_row, pw) reduced over the 16 lanes
    // (lr) that hold this row's 64 columns; then sigmoid.
    float pwv[4];
#pragma unroll
    for (int c = 0; c < 4; ++c) pwv[c] = pw[c * 16 + lr];
#pragma unroll
    for (int r = 0; r < 4; ++r) {
      float s_ = o_[0][r] * pwv[0] + o_[1][r] * pwv[1] +
                 o_[2][r] * pwv[2] + o_[3][r] * pwv[3];
#pragma unroll
      for (int off = 1; off < 16; off <<= 1) s_ += __shfl_xor(s_, off, 64);
      int grow = row0 + lg * 4 + r;
      if (lr == 0 && grow < N) {
        float logit = s_ + pb[0];
        predOut[grow] = 1.f / (1.f + expf(-logit));
      }
    }
  }
}

extern "C" void kernel_launch(void* const* d_in, const int* in_sizes, int n_in,
                              void* d_out, int out_size, void* d_ws, size_t ws_size,
                              hipStream_t stream) {
  const float* features = (const float*)d_in[0];
  const int* src = (const int*)d_in[1];
  const int* dst = (const int*)d_in[2];
  const int* et  = (const int*)d_in[3];
  const float* bases[3] = {(const float*)d_in[4], (const float*)d_in[8],  (const float*)d_in[12]};
  const float* comp[3]  = {(const float*)d_in[5], (const float*)d_in[9],  (const float*)d_in[13]};
  const float* loopw[3] = {(const float*)d_in[6], (const float*)d_in[10], (const float*)d_in[14]};
  const float* biasp[3] = {(const float*)d_in[7], (const float*)d_in[11], (const float*)d_in[15]};
  const float* pred_w = (const float*)d_in[16];
  const float* pred_b = (const float*)d_in[17];

  const int N = in_sizes[0] / 64;   // 100000
  const int E = in_sizes[1];        // 1600000

  char* ws = (char*)d_ws;
  size_t off = 0;
  auto take = [&](size_t bytes) {
    char* p = ws + off;
    off += (bytes + 255) & ~(size_t)255;
    return p;
  };
  int*      row_off     = (int*)     take((size_t)(N + 1) * 4);
  int*      H           = (int*)     take((size_t)NBLK1 * NB1 * 4);
  int*      total       = (int*)     take((size_t)NB1 * 4);
  int*      bucket_base = (int*)     take((size_t)(NB1 + 1) * 4);
  int*      epk         = (int*)     take((size_t)(E + 8) * 4);  // +pad
  ushort_t* Zh          = (ushort_t*)take((size_t)N * 128 * 2);
  ushort_t* xqA         = (ushort_t*)take((size_t)N * 64 * 2);
  ushort_t* xqB         = (ushort_t*)take((size_t)N * 64 * 2);
  int*      epk1        = (int*)Zh;   // alias: Zh dead during CSR build
  (void)ws_size;

  // ---- CSR build: 2-level counting sort, no global atomics
  int chunk = (E + NBLK1 - 1) / NBLK1;
  k_l1hist  <<<NBLK1, 256, 0, stream>>>(dst, H, E, chunk);
  k_colscan <<<NB1,   256, 0, stream>>>(H, total);
  k_basescan<<<1,     256, 0, stream>>>(total, bucket_base, row_off, N);
  k_scatter1<<<NBLK1, 256, 0, stream>>>(src, dst, et, H, bucket_base, epk1, E, chunk);
  k_bucket  <<<NB1,   256, 0, stream>>>(epk1, bucket_base, epk, row_off, N);

  // ---- quantize input features to fp16
  k_quant<<<(N * 16 + 255) / 256, 256, 0, stream>>>(features, xqA, N * 16);

  // ---- 3 RGCN layers (fp16 activations ping-pong); layer 3 fuses predictor
  ushort_t* bufs[2] = {xqA, xqB};
  int agg_grid = (N + 3) / 4;
  int gemm_grid = (N + 63) / 64;
  for (int l = 0; l < 3; ++l) {
    k_aggregate<<<agg_grid, 256, 0, stream>>>(bufs[l & 1], row_off, epk,
                                              comp[l], Zh, N);
    bool last = (l == 2);
    k_gemm_mfma<<<gemm_grid, 256, 0, stream>>>(
        Zh, bufs[l & 1], bases[l], loopw[l], biasp[l],
        last ? nullptr : bufs[(l + 1) & 1],
        pred_w, pred_b, last ? (float*)d_out : nullptr, N);
  }
}

// Round 12
// 331.544 us; speedup vs baseline: 1.5097x; 1.0934x over previous
//
#include <hip/hip_runtime.h>
#include <hip/hip_bf16.h>
#include <hip/hip_fp16.h>

// RGCN: 3 layers of basis-decomposed relational graph conv + predictor.
// CSR build via 2-level counting sort (NO global atomics).
// k_aggregate: wave/node fp16 gather — structural ~68us (205MB logical
//   random gather, ~60% L2 hit = capacity ratio, MLP cap saturated; R6
//   unroll null, R8/R9 XCD-slicing falsified, R11 nontemporal regressed).
//   PLAIN loads/stores (R11 post-mortem: nt hints +13% on this kernel).
// k_gemm_mfma: out = relu([Z|x] @ [bases;loop_w] + bias) via
//   mfma_f32_16x16x32_f16; W^T fp16 + residual staged in LDS (~2^-22
//   weight error). Last layer fuses the predictor:
//   sigmoid(out @ pred_w + pred_b) via 16-lane shfl reduce from fp32 accs.

#define NB1 196        // ceil(100000/512) coarse buckets
#define NBLK1 256      // L1 partition blocks
#define BUCKET_SHIFT 9 // 512 nodes per bucket
#define WT_LD 200      // padded k-stride (fp16) for W^T LDS: 400B = 2-way free

typedef unsigned short ushort_t;
typedef _Float16 h8 __attribute__((ext_vector_type(8)));
typedef float f32x4 __attribute__((ext_vector_type(4)));

__device__ inline ushort_t f2h(float f) {
  __half h = __float2half_rn(f);
  return *(ushort_t*)&h;
}
__device__ inline float h2f(ushort_t u) {
  __half h = *(__half*)&u;
  return __half2float(h);
}

// inclusive scan of one int per thread across a 256-thread block
__device__ inline int block_incl_scan_256(int v, int* wsums) {
  int lane = threadIdx.x & 63, wid = threadIdx.x >> 6;
  int s = v;
#pragma unroll
  for (int off = 1; off < 64; off <<= 1) {
    int u = __shfl_up(s, off, 64);
    if (lane >= off) s += u;
  }
  if (lane == 63) wsums[wid] = s;
  __syncthreads();
  if (threadIdx.x == 0) {
    int a = 0;
#pragma unroll
    for (int w = 0; w < 4; ++w) { int t = wsums[w]; wsums[w] = a; a += t; }
  }
  __syncthreads();
  return s + wsums[wid];
}

// ---- L1 pass a: per-block LDS histogram over 196 coarse buckets
__global__ void __launch_bounds__(256) k_l1hist(const int* __restrict__ dst,
                                                int* __restrict__ H, int E, int chunk) {
  __shared__ int h[NB1];
  int t = threadIdx.x;
  if (t < NB1) h[t] = 0;
  __syncthreads();
  int beg = blockIdx.x * chunk;
  int end = min(beg + chunk, E);
  for (int i = beg + t; i < end; i += 256) atomicAdd(&h[dst[i] >> BUCKET_SHIFT], 1);
  __syncthreads();
  if (t < NB1) H[blockIdx.x * NB1 + t] = h[t];
}

// ---- L1 pass b: scan each bucket's column of H -> excl offsets + totals
__global__ void __launch_bounds__(256) k_colscan(int* __restrict__ H,
                                                 int* __restrict__ total) {
  __shared__ int wsums[4];
  int b = blockIdx.x;
  int t = threadIdx.x;
  int v = H[t * NB1 + b];
  int s = block_incl_scan_256(v, wsums);
  H[t * NB1 + b] = s - v;
  if (t == 255) total[b] = s;
}

// ---- L1 pass c: scan bucket totals -> bucket_base
__global__ void __launch_bounds__(256) k_basescan(const int* __restrict__ total,
                                                  int* __restrict__ bucket_base,
                                                  int* __restrict__ row_off, int N) {
  __shared__ int wsums[4];
  int t = threadIdx.x;
  int v = (t < NB1) ? total[t] : 0;
  int s = block_incl_scan_256(v, wsums);
  if (t < NB1) bucket_base[t] = s - v;
  if (t == 255) { bucket_base[NB1] = s; row_off[N] = s; }
}

// ---- L1 pass d: scatter edges into bucket-partitioned epk1 via LDS cursors
__global__ void __launch_bounds__(256) k_scatter1(
    const int* __restrict__ src, const int* __restrict__ dst,
    const int* __restrict__ et, const int* __restrict__ H,
    const int* __restrict__ bucket_base, int* __restrict__ epk1,
    int E, int chunk) {
  __shared__ int cur[NB1];
  int t = threadIdx.x;
  if (t < NB1) cur[t] = bucket_base[t] + H[blockIdx.x * NB1 + t];
  __syncthreads();
  int beg = blockIdx.x * chunk;
  int end = min(beg + chunk, E);
  for (int i = beg + t; i < end; i += 256) {
    int d = dst[i];
    int b = d >> BUCKET_SHIFT;
    int p = atomicAdd(&cur[b], 1);
    epk1[p] = src[i] | (et[i] << 17) | ((d & 511) << 19);
  }
}

// ---- L2: per-bucket exact sort by dst_local (512 bins) -> epk + row_off
__global__ void __launch_bounds__(256) k_bucket(
    const int* __restrict__ epk1, const int* __restrict__ bucket_base,
    int* __restrict__ epk, int* __restrict__ row_off, int N) {
  __shared__ int hist[512];
  __shared__ int cur[512];
  __shared__ int wsums[4];
  int b = blockIdx.x;
  int t = threadIdx.x;
  int ebase = bucket_base[b], eend = bucket_base[b + 1];
  hist[t] = 0; hist[t + 256] = 0;
  __syncthreads();
  for (int i = ebase + t; i < eend; i += 256) atomicAdd(&hist[epk1[i] >> 19], 1);
  __syncthreads();
  int h0 = hist[2 * t], h1 = hist[2 * t + 1];
  int pair = h0 + h1;
  int incl = block_incl_scan_256(pair, wsums);
  int e0 = incl - pair;
  cur[2 * t] = ebase + e0;
  cur[2 * t + 1] = ebase + e0 + h0;
  int n0 = (b << BUCKET_SHIFT) + 2 * t;
  if (n0 < N) row_off[n0] = ebase + e0;
  if (n0 + 1 < N) row_off[n0 + 1] = ebase + e0 + h0;
  __syncthreads();
  for (int i = ebase + t; i < eend; i += 256) {
    int pk = epk1[i];
    int p = atomicAdd(&cur[pk >> 19], 1);
    epk[p] = pk;
  }
}

// ---- quantize fp32 -> fp16 (RTNE), vectorized
__global__ void __launch_bounds__(256) k_quant(const float* __restrict__ in,
                                               ushort_t* __restrict__ out, int n4) {
  int i = blockIdx.x * blockDim.x + threadIdx.x;
  if (i < n4) {
    float4 v = ((const float4*)in)[i];
    ushort4 q;
    q.x = f2h(v.x); q.y = f2h(v.y);
    q.z = f2h(v.z); q.w = f2h(v.w);
    ((ushort4*)out)[i] = q;
  }
}

// One wave per node; lane = channel. fp16 gather (128B/edge row), 8-deep
// unroll. Emits Z as fp16: Zh[node][0..63]=basis0, [64..127]=basis1.
__global__ void __launch_bounds__(256) k_aggregate(
    const ushort_t* __restrict__ xq, const int* __restrict__ row_off,
    const int* __restrict__ epk, const float* __restrict__ comp,
    ushort_t* __restrict__ Zh, int N) {
  __shared__ float s_comp[8];
  if (threadIdx.x < 8) s_comp[threadIdx.x] = comp[threadIdx.x];
  __syncthreads();
  int node = blockIdx.x * 4 + (threadIdx.x >> 6);
  int lane = threadIdx.x & 63;
  if (node >= N) return;
  int beg = row_off[node], end = row_off[node + 1];
  float z0 = 0.f, z1 = 0.f;
  int e = beg;
  for (; e + 7 < end; e += 8) {
    int pk[8];
    float xv[8];
#pragma unroll
    for (int u = 0; u < 8; ++u) pk[u] = epk[e + u];
#pragma unroll
    for (int u = 0; u < 8; ++u)
      xv[u] = h2f(xq[(size_t)(pk[u] & 0x1FFFF) * 64 + lane]);
#pragma unroll
    for (int u = 0; u < 8; ++u) {
      int r = (pk[u] >> 17) & 3;
      z0 = fmaf(s_comp[r * 2 + 0], xv[u], z0);
      z1 = fmaf(s_comp[r * 2 + 1], xv[u], z1);
    }
  }
  for (; e < end; ++e) {
    int pk = epk[e];
    int s = pk & 0x1FFFF, r = (pk >> 17) & 3;
    float xv = h2f(xq[(size_t)s * 64 + lane]);
    z0 = fmaf(s_comp[r * 2 + 0], xv, z0);
    z1 = fmaf(s_comp[r * 2 + 1], xv, z1);
  }
  Zh[(size_t)node * 128 + lane] = f2h(z0);
  Zh[(size_t)node * 128 + 64 + lane] = f2h(z1);
}

// ---- MFMA GEMM: out = relu([Z | x](64x192 fp16) @ W(192x64) + bias)
// A-frags from global (rows read once); W^T fp16 + residual in LDS.
// Optional fused predictor (last layer): sigmoid(out @ pw + pb).
// Layouts (mfma_f32_16x16x32_f16): A row=l&15, k=8*(l>>4)+j;
// B k=8*(l>>4)+j, col=l&15; C/D col=l&15, row=4*(l>>4)+reg.
__global__ void __launch_bounds__(256) k_gemm_mfma(
    const ushort_t* __restrict__ Zh, const ushort_t* __restrict__ xq,
    const float* __restrict__ bases, const float* __restrict__ loopw,
    const float* __restrict__ bias, ushort_t* __restrict__ xqOut,
    const float* __restrict__ pw, const float* __restrict__ pb,
    float* __restrict__ predOut, int N) {
  __shared__ ushort_t sWh[64 * WT_LD];  // W^T fp16:      25.6 KB
  __shared__ ushort_t sWr[64 * WT_LD];  // W^T residual:  25.6 KB
  int t = threadIdx.x;
  int w = t >> 6, l = t & 63;
  int lr = l & 15, lg = l >> 4;
  int row0 = blockIdx.x * 64 + w * 16;

  // ---- issue A-frag global loads FIRST (independent of LDS staging)
  int arow = row0 + lr;
  bool rok = arow < N;
  h8 a[6];
#pragma unroll
  for (int kb = 0; kb < 6; ++kb) {
    int k0 = kb * 32 + lg * 8;
    uint4 u = make_uint4(0, 0, 0, 0);
    if (rok) {
      if (kb < 4) u = *(const uint4*)(Zh + (size_t)arow * 128 + k0);
      else        u = *(const uint4*)(xq + (size_t)arow * 64 + (k0 - 128));
    }
    a[kb] = *(h8*)&u;
  }

  // ---- stage W^T as fp16 + residual (W = Wh + Wr exactly to ~2^-22)
#pragma unroll 4
  for (int i = 0; i < 48; ++i) {
    int idx = i * 256 + t;        // 0..12287
    int k = idx >> 6, c = idx & 63;
    float wv = (k < 128) ? bases[idx] : loopw[idx - 8192];
    ushort_t hh = f2h(wv);
    sWh[c * WT_LD + k] = hh;
    sWr[c * WT_LD + k] = f2h(wv - h2f(hh));
  }
  __syncthreads();

  // ---- MFMA: 4 col-tiles x 6 k-steps x (Wh + Wr)
  f32x4 acc[4];
#pragma unroll
  for (int c = 0; c < 4; ++c) acc[c] = (f32x4){0.f, 0.f, 0.f, 0.f};
#pragma unroll
  for (int c = 0; c < 4; ++c) {
    int col = c * 16 + lr;
    const ushort_t* bh = sWh + col * WT_LD + lg * 8;
    const ushort_t* br = sWr + col * WT_LD + lg * 8;
#pragma unroll
    for (int kb = 0; kb < 6; ++kb) {
      h8 vb = *(const h8*)(bh + kb * 32);
      acc[c] = __builtin_amdgcn_mfma_f32_16x16x32_f16(a[kb], vb, acc[c], 0, 0, 0);
      h8 vr = *(const h8*)(br + kb * 32);
      acc[c] = __builtin_amdgcn_mfma_f32_16x16x32_f16(a[kb], vr, acc[c], 0, 0, 0);
    }
  }

  // ---- epilogue: bias + relu
  float o_[4][4];
#pragma unroll
  for (int c = 0; c < 4; ++c) {
    float bv = bias[c * 16 + lr];
#pragma unroll
    for (int r = 0; r < 4; ++r) o_[c][r] = fmaxf(acc[c][r] + bv, 0.f);
  }
  if (xqOut) {
#pragma unroll
    for (int c = 0; c < 4; ++c) {
      int col = c * 16 + lr;
#pragma unroll
      for (int r = 0; r < 4; ++r) {
        int grow = row0 + lg * 4 + r;
        if (grow < N)
          xqOut[(size_t)grow * 64 + col] = f2h(o_[c][r]);
      }
    }
  }
  if (predOut) {
    // fused predictor: per row, dot(out_row, pw) reduced over the 16 lanes
    // (lr) that hold this row's 64 columns; then sigmoid.
    float pwv[4];
#pragma unroll
    for (int c = 0; c < 4; ++c) pwv[c] = pw[c * 16 + lr];
#pragma unroll
    for (int r = 0; r < 4; ++r) {
      float s_ = o_[0][r] * pwv[0] + o_[1][r] * pwv[1] +
                 o_[2][r] * pwv[2] + o_[3][r] * pwv[3];
#pragma unroll
      for (int off = 1; off < 16; off <<= 1) s_ += __shfl_xor(s_, off, 64);
      int grow = row0 + lg * 4 + r;
      if (lr == 0 && grow < N) {
        float logit = s_ + pb[0];
        predOut[grow] = 1.f / (1.f + expf(-logit));
      }
    }
  }
}

extern "C" void kernel_launch(void* const* d_in, const int* in_sizes, int n_in,
                              void* d_out, int out_size, void* d_ws, size_t ws_size,
                              hipStream_t stream) {
  const float* features = (const float*)d_in[0];
  const int* src = (const int*)d_in[1];
  const int* dst = (const int*)d_in[2];
  const int* et  = (const int*)d_in[3];
  const float* bases[3] = {(const float*)d_in[4], (const float*)d_in[8],  (const float*)d_in[12]};
  const float* comp[3]  = {(const float*)d_in[5], (const float*)d_in[9],  (const float*)d_in[13]};
  const float* loopw[3] = {(const float*)d_in[6], (const float*)d_in[10], (const float*)d_in[14]};
  const float* biasp[3] = {(const float*)d_in[7], (const float*)d_in[11], (const float*)d_in[15]};
  const float* pred_w = (const float*)d_in[16];
  const float* pred_b = (const float*)d_in[17];

  const int N = in_sizes[0] / 64;   // 100000
  const int E = in_sizes[1];        // 1600000

  char* ws = (char*)d_ws;
  size_t off = 0;
  auto take = [&](size_t bytes) {
    char* p = ws + off;
    off += (bytes + 255) & ~(size_t)255;
    return p;
  };
  int*      row_off     = (int*)     take((size_t)(N + 1) * 4);
  int*      H           = (int*)     take((size_t)NBLK1 * NB1 * 4);
  int*      total       = (int*)     take((size_t)NB1 * 4);
  int*      bucket_base = (int*)     take((size_t)(NB1 + 1) * 4);
  int*      epk         = (int*)     take((size_t)(E + 8) * 4);  // +pad
  ushort_t* Zh          = (ushort_t*)take((size_t)N * 128 * 2);
  ushort_t* xqA         = (ushort_t*)take((size_t)N * 64 * 2);
  ushort_t* xqB         = (ushort_t*)take((size_t)N * 64 * 2);
  int*      epk1        = (int*)Zh;   // alias: Zh dead during CSR build
  (void)ws_size;

  // ---- CSR build: 2-level counting sort, no global atomics
  int chunk = (E + NBLK1 - 1) / NBLK1;
  k_l1hist  <<<NBLK1, 256, 0, stream>>>(dst, H, E, chunk);
  k_colscan <<<NB1,   256, 0, stream>>>(H, total);
  k_basescan<<<1,     256, 0, stream>>>(total, bucket_base, row_off, N);
  k_scatter1<<<NBLK1, 256, 0, stream>>>(src, dst, et, H, bucket_base, epk1, E, chunk);
  k_bucket  <<<NB1,   256, 0, stream>>>(epk1, bucket_base, epk, row_off, N);

  // ---- quantize input features to fp16
  k_quant<<<(N * 16 + 255) / 256, 256, 0, stream>>>(features, xqA, N * 16);

  // ---- 3 RGCN layers (fp16 activations ping-pong); layer 3 fuses predictor
  ushort_t* bufs[2] = {xqA, xqB};
  int agg_grid = (N + 3) / 4;
  int gemm_grid = (N + 63) / 64;
  for (int l = 0; l < 3; ++l) {
    k_aggregate<<<agg_grid, 256, 0, stream>>>(bufs[l & 1], row_off, epk,
                                              comp[l], Zh, N);
    bool last = (l == 2);
    k_gemm_mfma<<<gemm_grid, 256, 0, stream>>>(
        Zh, bufs[l & 1], bases[l], loopw[l], biasp[l],
        last ? nullptr : bufs[(l + 1) & 1],
        pred_w, pred_b, last ? (float*)d_out : nullptr, N);
  }
}

// Round 13
// 276.595 us; speedup vs baseline: 1.8097x; 1.1987x over previous
//
#include <hip/hip_runtime.h>
#include <hip/hip_bf16.h>
#include <hip/hip_fp16.h>

// RGCN: 3 layers of basis-decomposed relational graph conv + predictor.
// CSR build via 2-level counting sort (NO global atomics). Edge lists are
//   PADDED to multiples of 8 per node with dummy edges (rel=4, comp[4]=0,
//   src=0) so the aggregate hot loop is mask-free and batches never span
//   nodes. Pack: src | et<<17 (3 bits) | dst_local<<20.
// k_aggregate: SOFTWARE-PIPELINED gather (2-slot ping-pong): issue batch
//   k+1's 8 gathers BEFORE consuming batch k -> counted vmcnt, ~16 gathers
//   in flight/wave (R12 counter arithmetic: old loop sustained only ~1/wave;
//   duty-cycle-limited, not HW-cap-limited). Wave = 8 sequential nodes.
// k_gemm_mfma: out = relu([Z|x] @ [bases;loop_w] + bias) via
//   mfma_f32_16x16x32_f16; W^T fp16 + residual in LDS (~2^-22 weight err).
//   Last layer fuses predictor: sigmoid(out @ pred_w + pred_b).

#define NB1 196        // ceil(100000/512) coarse buckets
#define NBLK1 256      // L1 partition blocks
#define BUCKET_SHIFT 9 // 512 nodes per bucket
#define PAD_ALLOW 4096 // per-bucket padding allowance (512 nodes x <=8)
#define WT_LD 200      // padded k-stride (fp16) for W^T LDS
#define DUMMY_PK (4 << 17)
#define WNODES 8       // nodes per wave in aggregate

typedef unsigned short ushort_t;
typedef _Float16 h8 __attribute__((ext_vector_type(8)));
typedef float f32x4 __attribute__((ext_vector_type(4)));

__device__ inline ushort_t f2h(float f) {
  __half h = __float2half_rn(f);
  return *(ushort_t*)&h;
}
__device__ inline float h2f(ushort_t u) {
  __half h = *(__half*)&u;
  return __half2float(h);
}

// inclusive scan of one int per thread across a 256-thread block
__device__ inline int block_incl_scan_256(int v, int* wsums) {
  int lane = threadIdx.x & 63, wid = threadIdx.x >> 6;
  int s = v;
#pragma unroll
  for (int off = 1; off < 64; off <<= 1) {
    int u = __shfl_up(s, off, 64);
    if (lane >= off) s += u;
  }
  if (lane == 63) wsums[wid] = s;
  __syncthreads();
  if (threadIdx.x == 0) {
    int a = 0;
#pragma unroll
    for (int w = 0; w < 4; ++w) { int t = wsums[w]; wsums[w] = a; a += t; }
  }
  __syncthreads();
  return s + wsums[wid];
}

// ---- L1 pass a: per-block LDS histogram over 196 coarse buckets
__global__ void __launch_bounds__(256) k_l1hist(const int* __restrict__ dst,
                                                int* __restrict__ H, int E, int chunk) {
  __shared__ int h[NB1];
  int t = threadIdx.x;
  if (t < NB1) h[t] = 0;
  __syncthreads();
  int beg = blockIdx.x * chunk;
  int end = min(beg + chunk, E);
  for (int i = beg + t; i < end; i += 256) atomicAdd(&h[dst[i] >> BUCKET_SHIFT], 1);
  __syncthreads();
  if (t < NB1) H[blockIdx.x * NB1 + t] = h[t];
}

// ---- L1 pass b: scan each bucket's column of H -> excl offsets + totals
__global__ void __launch_bounds__(256) k_colscan(int* __restrict__ H,
                                                 int* __restrict__ total) {
  __shared__ int wsums[4];
  int b = blockIdx.x;
  int t = threadIdx.x;
  int v = H[t * NB1 + b];
  int s = block_incl_scan_256(v, wsums);
  H[t * NB1 + b] = s - v;
  if (t == 255) total[b] = s;
}

// ---- L1 pass c: scan bucket totals -> bucket_base
__global__ void __launch_bounds__(256) k_basescan(const int* __restrict__ total,
                                                  int* __restrict__ bucket_base) {
  __shared__ int wsums[4];
  int t = threadIdx.x;
  int v = (t < NB1) ? total[t] : 0;
  int s = block_incl_scan_256(v, wsums);
  if (t < NB1) bucket_base[t] = s - v;
  if (t == 255) bucket_base[NB1] = s;
}

// ---- L1 pass d: scatter edges into bucket-partitioned epk1 via LDS cursors
__global__ void __launch_bounds__(256) k_scatter1(
    const int* __restrict__ src, const int* __restrict__ dst,
    const int* __restrict__ et, const int* __restrict__ H,
    const int* __restrict__ bucket_base, int* __restrict__ epk1,
    int E, int chunk) {
  __shared__ int cur[NB1];
  int t = threadIdx.x;
  if (t < NB1) cur[t] = bucket_base[t] + H[blockIdx.x * NB1 + t];
  __syncthreads();
  int beg = blockIdx.x * chunk;
  int end = min(beg + chunk, E);
  for (int i = beg + t; i < end; i += 256) {
    int d = dst[i];
    int b = d >> BUCKET_SHIFT;
    int p = atomicAdd(&cur[b], 1);
    epk1[p] = src[i] | (et[i] << 17) | ((d & 511) << 20);
  }
}

// ---- L2: per-bucket sort by dst_local (512 bins) into PADDED epk
// (each node's segment rounded up to a multiple of 8; pads = DUMMY_PK).
__global__ void __launch_bounds__(256) k_bucket(
    const int* __restrict__ epk1, const int* __restrict__ bucket_base,
    int* __restrict__ epk, int* __restrict__ row_off,
    int* __restrict__ row_end, int N) {
  __shared__ int hist[512];
  __shared__ int cur[512];
  __shared__ int wsums[4];
  int b = blockIdx.x;
  int t = threadIdx.x;
  int ebase = bucket_base[b], eend = bucket_base[b + 1];
  int pb = ebase + b * PAD_ALLOW;   // padded region base
  hist[t] = 0; hist[t + 256] = 0;
  __syncthreads();
  for (int i = ebase + t; i < eend; i += 256) atomicAdd(&hist[epk1[i] >> 20], 1);
  __syncthreads();
  int h0 = hist[2 * t], h1 = hist[2 * t + 1];
  int pd0 = (h0 == 0) ? 8 : ((h0 + 7) & ~7);
  int pd1 = (h1 == 0) ? 8 : ((h1 + 7) & ~7);
  int pair = pd0 + pd1;
  int incl = block_incl_scan_256(pair, wsums);
  int pe0 = incl - pair;
  int s0 = pb + pe0, s1 = pb + pe0 + pd0;
  cur[2 * t] = s0;
  cur[2 * t + 1] = s1;
  int n0 = (b << BUCKET_SHIFT) + 2 * t;
  if (n0 < N)     { row_off[n0] = s0;     row_end[n0] = s0 + pd0; }
  if (n0 + 1 < N) { row_off[n0 + 1] = s1; row_end[n0 + 1] = s1 + pd1; }
  // fill pad slots (disjoint from scatter targets; no sync needed)
  for (int p = s0 + h0; p < s0 + pd0; ++p) epk[p] = DUMMY_PK;
  for (int p = s1 + h1; p < s1 + pd1; ++p) epk[p] = DUMMY_PK;
  __syncthreads();
  for (int i = ebase + t; i < eend; i += 256) {
    int pk = epk1[i];
    int p = atomicAdd(&cur[pk >> 20], 1);
    epk[p] = pk;
  }
}

// ---- quantize fp32 -> fp16 (RTNE), vectorized
__global__ void __launch_bounds__(256) k_quant(const float* __restrict__ in,
                                               ushort_t* __restrict__ out, int n4) {
  int i = blockIdx.x * blockDim.x + threadIdx.x;
  if (i < n4) {
    float4 v = ((const float4*)in)[i];
    ushort4 q;
    q.x = f2h(v.x); q.y = f2h(v.y);
    q.z = f2h(v.z); q.w = f2h(v.w);
    ((ushort4*)out)[i] = q;
  }
}

// ---- pipelined aggregate: wave = WNODES sequential nodes; two batch slots
// ping-pong so ~16 gathers stay in flight while consuming the previous 8.
// Batches are mask-free (padded edge lists; comp[4]=0 kills dummies).
__global__ void __launch_bounds__(256) k_aggregate(
    const ushort_t* __restrict__ xq, const int* __restrict__ row_off,
    const int* __restrict__ row_end, const int* __restrict__ epk,
    const float* __restrict__ comp, ushort_t* __restrict__ Zh, int N) {
  __shared__ float s_comp[10];
  if (threadIdx.x < 10)
    s_comp[threadIdx.x] = (threadIdx.x < 8) ? comp[threadIdx.x] : 0.f;
  __syncthreads();
  int lane = threadIdx.x & 63;
  int wnode0 = (blockIdx.x * 4 + (threadIdx.x >> 6)) * WNODES;
  if (wnode0 >= N) return;
  int wnode1 = min(wnode0 + WNODES, N);

  // issue cursor (wave-uniform)
  int nj = wnode0;
  int ej = row_off[nj], ejEnd = row_end[nj];

  int pkA[8], pkB[8];
  ushort_t xvA[8], xvB[8];
  int nodeA = wnode0, nodeB = wnode0;

#define ISSUE(PK, XV, NODE)                                                 \
  {                                                                         \
    NODE = nj;                                                              \
    _Pragma("unroll") for (int u = 0; u < 8; ++u) PK[u] = epk[ej + u];      \
    _Pragma("unroll") for (int u = 0; u < 8; ++u)                           \
        XV[u] = xq[(size_t)(PK[u] & 0x1FFFF) * 64 + lane];                  \
    ej += 8;                                                                \
    if (ej >= ejEnd) {                                                      \
      if (nj + 1 < wnode1) { ++nj; ej = row_off[nj]; ejEnd = row_end[nj]; } \
      else nj = -1;                                                         \
    }                                                                       \
  }

  int ncons = wnode0;
  float z0 = 0.f, z1 = 0.f;

#define CONSUME(PK, XV, NODE)                                               \
  {                                                                         \
    if (NODE != ncons) {                                                    \
      Zh[(size_t)ncons * 128 + lane] = f2h(z0);                             \
      Zh[(size_t)ncons * 128 + 64 + lane] = f2h(z1);                        \
      z0 = 0.f; z1 = 0.f; ncons = NODE;                                     \
    }                                                                       \
    _Pragma("unroll") for (int u = 0; u < 8; ++u) {                         \
      int r = (PK[u] >> 17) & 7;                                            \
      float xf = h2f(XV[u]);                                                \
      z0 = fmaf(s_comp[r * 2 + 0], xf, z0);                                 \
      z1 = fmaf(s_comp[r * 2 + 1], xf, z1);                                 \
    }                                                                       \
  }

  ISSUE(pkA, xvA, nodeA);
  for (;;) {
    bool haveB = (nj >= 0);
    if (haveB) ISSUE(pkB, xvB, nodeB);
    CONSUME(pkA, xvA, nodeA);
    if (!haveB) break;
    bool haveA = (nj >= 0);
    if (haveA) ISSUE(pkA, xvA, nodeA);
    CONSUME(pkB, xvB, nodeB);
    if (!haveA) break;
  }
  // final flush
  Zh[(size_t)ncons * 128 + lane] = f2h(z0);
  Zh[(size_t)ncons * 128 + 64 + lane] = f2h(z1);
#undef ISSUE
#undef CONSUME
}

// ---- MFMA GEMM: out = relu([Z | x](64x192 fp16) @ W(192x64) + bias)
// A-frags from global (rows read once); W^T fp16 + residual in LDS.
// Optional fused predictor (last layer): sigmoid(out @ pw + pb).
// Layouts (mfma_f32_16x16x32_f16): A row=l&15, k=8*(l>>4)+j;
// B k=8*(l>>4)+j, col=l&15; C/D col=l&15, row=4*(l>>4)+reg.
__global__ void __launch_bounds__(256) k_gemm_mfma(
    const ushort_t* __restrict__ Zh, const ushort_t* __restrict__ xq,
    const float* __restrict__ bases, const float* __restrict__ loopw,
    const float* __restrict__ bias, ushort_t* __restrict__ xqOut,
    const float* __restrict__ pw, const float* __restrict__ pb,
    float* __restrict__ predOut, int N) {
  __shared__ ushort_t sWh[64 * WT_LD];  // W^T fp16:      25.6 KB
  __shared__ ushort_t sWr[64 * WT_LD];  // W^T residual:  25.6 KB
  int t = threadIdx.x;
  int w = t >> 6, l = t & 63;
  int lr = l & 15, lg = l >> 4;
  int row0 = blockIdx.x * 64 + w * 16;

  // ---- issue A-frag global loads FIRST (independent of LDS staging)
  int arow = row0 + lr;
  bool rok = arow < N;
  h8 a[6];
#pragma unroll
  for (int kb = 0; kb < 6; ++kb) {
    int k0 = kb * 32 + lg * 8;
    uint4 u = make_uint4(0, 0, 0, 0);
    if (rok) {
      if (kb < 4) u = *(const uint4*)(Zh + (size_t)arow * 128 + k0);
      else        u = *(const uint4*)(xq + (size_t)arow * 64 + (k0 - 128));
    }
    a[kb] = *(h8*)&u;
  }

  // ---- stage W^T as fp16 + residual (W = Wh + Wr exactly to ~2^-22)
#pragma unroll 4
  for (int i = 0; i < 48; ++i) {
    int idx = i * 256 + t;        // 0..12287
    int k = idx >> 6, c = idx & 63;
    float wv = (k < 128) ? bases[idx] : loopw[idx - 8192];
    ushort_t hh = f2h(wv);
    sWh[c * WT_LD + k] = hh;
    sWr[c * WT_LD + k] = f2h(wv - h2f(hh));
  }
  __syncthreads();

  // ---- MFMA: 4 col-tiles x 6 k-steps x (Wh + Wr)
  f32x4 acc[4];
#pragma unroll
  for (int c = 0; c < 4; ++c) acc[c] = (f32x4){0.f, 0.f, 0.f, 0.f};
#pragma unroll
  for (int c = 0; c < 4; ++c) {
    int col = c * 16 + lr;
    const ushort_t* bh = sWh + col * WT_LD + lg * 8;
    const ushort_t* br = sWr + col * WT_LD + lg * 8;
#pragma unroll
    for (int kb = 0; kb < 6; ++kb) {
      h8 vb = *(const h8*)(bh + kb * 32);
      acc[c] = __builtin_amdgcn_mfma_f32_16x16x32_f16(a[kb], vb, acc[c], 0, 0, 0);
      h8 vr = *(const h8*)(br + kb * 32);
      acc[c] = __builtin_amdgcn_mfma_f32_16x16x32_f16(a[kb], vr, acc[c], 0, 0, 0);
    }
  }

  // ---- epilogue: bias + relu
  float o_[4][4];
#pragma unroll
  for (int c = 0; c < 4; ++c) {
    float bv = bias[c * 16 + lr];
#pragma unroll
    for (int r = 0; r < 4; ++r) o_[c][r] = fmaxf(acc[c][r] + bv, 0.f);
  }
  if (xqOut) {
#pragma unroll
    for (int c = 0; c < 4; ++c) {
      int col = c * 16 + lr;
#pragma unroll
      for (int r = 0; r < 4; ++r) {
        int grow = row0 + lg * 4 + r;
        if (grow < N)
          xqOut[(size_t)grow * 64 + col] = f2h(o_[c][r]);
      }
    }
  }
  if (predOut) {
    float pwv[4];
#pragma unroll
    for (int c = 0; c < 4; ++c) pwv[c] = pw[c * 16 + lr];
#pragma unroll
    for (int r = 0; r < 4; ++r) {
      float s_ = o_[0][r] * pwv[0] + o_[1][r] * pwv[1] +
                 o_[2][r] * pwv[2] + o_[3][r] * pwv[3];
#pragma unroll
      for (int off = 1; off < 16; off <<= 1) s_ += __shfl_xor(s_, off, 64);
      int grow = row0 + lg * 4 + r;
      if (lr == 0 && grow < N) {
        float logit = s_ + pb[0];
        predOut[grow] = 1.f / (1.f + expf(-logit));
      }
    }
  }
}

extern "C" void kernel_launch(void* const* d_in, const int* in_sizes, int n_in,
                              void* d_out, int out_size, void* d_ws, size_t ws_size,
                              hipStream_t stream) {
  const float* features = (const float*)d_in[0];
  const int* src = (const int*)d_in[1];
  const int* dst = (const int*)d_in[2];
  const int* et  = (const int*)d_in[3];
  const float* bases[3] = {(const float*)d_in[4], (const float*)d_in[8],  (const float*)d_in[12]};
  const float* comp[3]  = {(const float*)d_in[5], (const float*)d_in[9],  (const float*)d_in[13]};
  const float* loopw[3] = {(const float*)d_in[6], (const float*)d_in[10], (const float*)d_in[14]};
  const float* biasp[3] = {(const float*)d_in[7], (const float*)d_in[11], (const float*)d_in[15]};
  const float* pred_w = (const float*)d_in[16];
  const float* pred_b = (const float*)d_in[17];

  const int N = in_sizes[0] / 64;   // 100000
  const int E = in_sizes[1];        // 1600000

  char* ws = (char*)d_ws;
  size_t off = 0;
  auto take = [&](size_t bytes) {
    char* p = ws + off;
    off += (bytes + 255) & ~(size_t)255;
    return p;
  };
  int*      row_off     = (int*)     take((size_t)(N + 1) * 4);
  int*      row_end     = (int*)     take((size_t)N * 4);
  int*      H           = (int*)     take((size_t)NBLK1 * NB1 * 4);
  int*      total       = (int*)     take((size_t)NB1 * 4);
  int*      bucket_base = (int*)     take((size_t)(NB1 + 1) * 4);
  int*      epk         = (int*)     take((size_t)(E + NB1 * PAD_ALLOW + 8) * 4);
  ushort_t* Zh          = (ushort_t*)take((size_t)N * 128 * 2);
  ushort_t* xqA         = (ushort_t*)take((size_t)N * 64 * 2);
  ushort_t* xqB         = (ushort_t*)take((size_t)N * 64 * 2);
  int*      epk1        = (int*)Zh;   // alias: Zh dead during CSR build
  (void)ws_size;

  // ---- CSR build: 2-level counting sort, no global atomics
  int chunk = (E + NBLK1 - 1) / NBLK1;
  k_l1hist  <<<NBLK1, 256, 0, stream>>>(dst, H, E, chunk);
  k_colscan <<<NB1,   256, 0, stream>>>(H, total);
  k_basescan<<<1,     256, 0, stream>>>(total, bucket_base);
  k_scatter1<<<NBLK1, 256, 0, stream>>>(src, dst, et, H, bucket_base, epk1, E, chunk);
  k_bucket  <<<NB1,   256, 0, stream>>>(epk1, bucket_base, epk, row_off, row_end, N);

  // ---- quantize input features to fp16
  k_quant<<<(N * 16 + 255) / 256, 256, 0, stream>>>(features, xqA, N * 16);

  // ---- 3 RGCN layers (fp16 activations ping-pong); layer 3 fuses predictor
  ushort_t* bufs[2] = {xqA, xqB};
  int agg_grid = (N + 4 * WNODES - 1) / (4 * WNODES);
  int gemm_grid = (N + 63) / 64;
  for (int l = 0; l < 3; ++l) {
    k_aggregate<<<agg_grid, 256, 0, stream>>>(bufs[l & 1], row_off, row_end,
                                              epk, comp[l], Zh, N);
    bool last = (l == 2);
    k_gemm_mfma<<<gemm_grid, 256, 0, stream>>>(
        Zh, bufs[l & 1], bases[l], loopw[l], biasp[l],
        last ? nullptr : bufs[(l + 1) & 1],
        pred_w, pred_b, last ? (float*)d_out : nullptr, N);
  }
}